// Round 1
// baseline (2603.411 us; speedup 1.0000x reference)
//
#include <hip/hip_runtime.h>
#include <math.h>

#define DD   1024
#define BB   64
#define SS   128
#define DINN 64
#define DOUTN 64

// ---------------------------------------------------------------------------
// Small guarded GEMM for precompute stages (64x64 tile, 4x4 micro).
// C[M,N] = A[M,K] @ W   (W: [K,N] row-major, or [N,K] if TRANSW)
// ---------------------------------------------------------------------------
template<bool TRANSW>
__global__ __launch_bounds__(256)
void k_gemm_small(const float* __restrict__ A, int lda,
                  const float* __restrict__ W, int ldw,
                  float* __restrict__ C, int ldc,
                  int M, int N, int K) {
  __shared__ float As[16][64];
  __shared__ float Ws[16][64];
  const int tx = threadIdx.x & 15, ty = threadIdx.x >> 4;
  const int row0 = blockIdx.y * 64, col0 = blockIdx.x * 64;
  float acc[4][4] = {};
  for (int k0 = 0; k0 < K; k0 += 16) {
    const int u = threadIdx.x;
    {
      const int ar = u >> 2, ac4 = (u & 3) * 4;
      const int r = row0 + ar;
#pragma unroll
      for (int j = 0; j < 4; ++j)
        As[ac4 + j][ar] = (r < M) ? A[r * lda + k0 + ac4 + j] : 0.f;
    }
    if (!TRANSW) {
      const int kk = u >> 4, c4 = (u & 15) * 4;
#pragma unroll
      for (int j = 0; j < 4; ++j) {
        const int c = col0 + c4 + j;
        Ws[kk][c4 + j] = (c < N) ? W[(k0 + kk) * ldw + c] : 0.f;
      }
    } else {
      const int nn = u >> 2, kk4 = (u & 3) * 4;
      const int c = col0 + nn;
#pragma unroll
      for (int j = 0; j < 4; ++j)
        Ws[kk4 + j][nn] = (c < N) ? W[c * ldw + k0 + kk4 + j] : 0.f;
    }
    __syncthreads();
#pragma unroll
    for (int kk = 0; kk < 16; ++kk) {
      float a[4], b[4];
#pragma unroll
      for (int i = 0; i < 4; ++i) a[i] = As[kk][ty * 4 + i];
#pragma unroll
      for (int j = 0; j < 4; ++j) b[j] = Ws[kk][tx * 4 + j];
#pragma unroll
      for (int i = 0; i < 4; ++i)
#pragma unroll
        for (int j = 0; j < 4; ++j) acc[i][j] += a[i] * b[j];
    }
    __syncthreads();
  }
#pragma unroll
  for (int i = 0; i < 4; ++i) {
    const int r = row0 + ty * 4 + i;
    if (r >= M) continue;
#pragma unroll
    for (int j = 0; j < 4; ++j) {
      const int c = col0 + tx * 4 + j;
      if (c < N) C[r * ldc + c] = acc[i][j];
    }
  }
}

// ---------------------------------------------------------------------------
// Main tiled GEMM: 128x128 tile, BK=16, 8x8 micro-tile, 256 threads.
// SHIFT: rows are laid [S,B] (row r -> t = r>>6); A-col index and C-col index
//        are rolled by +t (mod 1024)  ==> implements roll(roll(h,-t)@W, t).
// TRANSW: multiply by W^T (W accessed [n,k]).
// EPI:   C[r,c] = C_old[r,c] + tanh(acc)   (reversible-coupling epilogue)
// Dims must be multiples of the tile (M=8192, N in {512,1024}, K in {512,1024}).
// ---------------------------------------------------------------------------
template<bool SHIFT, bool TRANSW, bool EPI>
__global__ __launch_bounds__(256)
void k_gemm_big(const float* __restrict__ A, int lda,
                const float* __restrict__ W, int ldw,
                float* __restrict__ C, int ldc, int K) {
  __shared__ float As[16][128];
  __shared__ float Ws[16][128];
  const int tx = threadIdx.x & 15, ty = threadIdx.x >> 4;
  const int row0 = blockIdx.y * 128, col0 = blockIdx.x * 128;
  float acc[8][8] = {};
  for (int k0 = 0; k0 < K; k0 += 16) {
    const int u = threadIdx.x;
    {
      const int ar = u >> 2;        // 0..63
      const int ac4 = (u & 3) * 4;  // 0,4,8,12
#pragma unroll
      for (int rr = 0; rr < 2; ++rr) {
        const int m = ar + rr * 64;
        const int grow = row0 + m;
        if (SHIFT) {
          const int t = grow >> 6;
#pragma unroll
          for (int j = 0; j < 4; ++j) {
            const int gc = (k0 + ac4 + j + t) & (DD - 1);
            As[ac4 + j][m] = A[grow * lda + gc];
          }
        } else {
          const float4 v = *(const float4*)&A[grow * lda + k0 + ac4];
          As[ac4 + 0][m] = v.x; As[ac4 + 1][m] = v.y;
          As[ac4 + 2][m] = v.z; As[ac4 + 3][m] = v.w;
        }
      }
    }
    if (!TRANSW) {
      const int kk = u >> 4;            // 0..15
      const int c8 = (u & 15) * 8;      // 0..120
      const float4 v0 = *(const float4*)&W[(k0 + kk) * ldw + col0 + c8];
      const float4 v1 = *(const float4*)&W[(k0 + kk) * ldw + col0 + c8 + 4];
      *(float4*)&Ws[kk][c8]     = v0;
      *(float4*)&Ws[kk][c8 + 4] = v1;
    } else {
      const int nn = u >> 2;            // 0..63
      const int kk4 = (u & 3) * 4;
#pragma unroll
      for (int rr = 0; rr < 2; ++rr) {
        const int n = nn + rr * 64;
        const float4 v = *(const float4*)&W[(col0 + n) * ldw + k0 + kk4];
        Ws[kk4 + 0][n] = v.x; Ws[kk4 + 1][n] = v.y;
        Ws[kk4 + 2][n] = v.z; Ws[kk4 + 3][n] = v.w;
      }
    }
    __syncthreads();
#pragma unroll
    for (int kk = 0; kk < 16; ++kk) {
      float a[8], b[8];
      *(float4*)&a[0] = *(const float4*)&As[kk][ty * 8];
      *(float4*)&a[4] = *(const float4*)&As[kk][ty * 8 + 4];
      *(float4*)&b[0] = *(const float4*)&Ws[kk][tx * 8];
      *(float4*)&b[4] = *(const float4*)&Ws[kk][tx * 8 + 4];
#pragma unroll
      for (int i = 0; i < 8; ++i)
#pragma unroll
        for (int j = 0; j < 8; ++j) acc[i][j] += a[i] * b[j];
    }
    __syncthreads();
  }
#pragma unroll
  for (int i = 0; i < 8; ++i) {
    const int grow = row0 + ty * 8 + i;
    const int t = SHIFT ? (grow >> 6) : 0;
#pragma unroll
    for (int j = 0; j < 8; ++j) {
      int gc = col0 + tx * 8 + j;
      if (SHIFT) gc = (gc + t) & (DD - 1);
      float v = acc[i][j];
      if (EPI) v = C[grow * ldc + gc] + tanhf(v);
      C[grow * ldc + gc] = v;
    }
  }
}

// ---------------------------------------------------------------------------
// S_refl = R + R^T
// ---------------------------------------------------------------------------
__global__ void k_symm(const float* __restrict__ R, float* __restrict__ S) {
  const int idx = blockIdx.x * 256 + threadIdx.x;
  const int i = idx >> 10, j = idx & (DD - 1);
  S[idx] = R[idx] + R[j * DD + i];
}

// cvec = P @ bi
__global__ void k_matvec(const float* __restrict__ P, const float* __restrict__ b,
                         float* __restrict__ c) {
  const int i = blockIdx.x * 256 + threadIdx.x;
  float acc = 0.f;
  for (int j = 0; j < DD; ++j) acc += P[i * DD + j] * b[j];
  c[i] = acc;
}

// ---------------------------------------------------------------------------
// h0[r, :] = x[b, t, :] @ A2^T + cvec   with r = t*64 + b, A2: [D, DIN]
// 16 rows per block.
// ---------------------------------------------------------------------------
__global__ __launch_bounds__(256)
void k_in(const float* __restrict__ x, const float* __restrict__ A2,
          const float* __restrict__ cvec, float* __restrict__ ha) {
  const int r0 = blockIdx.x * 16;
  __shared__ float xs[16][DINN];
  const int u = threadIdx.x;
  for (int i = u; i < 16 * DINN; i += 256) {
    const int rr = i >> 6, k = i & 63;
    const int r = r0 + rr, t = r >> 6, b = r & 63;
    xs[rr][k] = x[(b * SS + t) * DINN + k];
  }
  __syncthreads();
  float acc[4][16];
#pragma unroll
  for (int q = 0; q < 4; ++q) {
    const float cv = cvec[u + q * 256];
#pragma unroll
    for (int rr = 0; rr < 16; ++rr) acc[q][rr] = cv;
  }
  for (int k = 0; k < DINN; ++k) {
    float a[4];
#pragma unroll
    for (int q = 0; q < 4; ++q) a[q] = A2[(u + q * 256) * DINN + k];
#pragma unroll
    for (int rr = 0; rr < 16; ++rr) {
      const float xv = xs[rr][k];
#pragma unroll
      for (int q = 0; q < 4; ++q) acc[q][rr] += a[q] * xv;
    }
  }
#pragma unroll
  for (int rr = 0; rr < 16; ++rr)
#pragma unroll
    for (int q = 0; q < 4; ++q)
      ha[(r0 + rr) * DD + u + q * 256] = acc[q][rr];
}

// ---------------------------------------------------------------------------
// out[b, t, :] = h[r, :] @ Mout + bo   with r = t*64 + b, Mout: [D, DOUT]
// 16 rows per block; 256 threads = 4 row-groups x 64 cols.
// ---------------------------------------------------------------------------
__global__ __launch_bounds__(256)
void k_out(const float* __restrict__ hb, const float* __restrict__ Mout,
           const float* __restrict__ bo, float* __restrict__ out) {
  const int r0 = blockIdx.x * 16;
  const int c = threadIdx.x & 63;
  const int rq = threadIdx.x >> 6;  // 0..3
  float acc[4] = {0.f, 0.f, 0.f, 0.f};
  for (int d0 = 0; d0 < DD; d0 += 4) {
    float m[4];
#pragma unroll
    for (int j = 0; j < 4; ++j) m[j] = Mout[(d0 + j) * DOUTN + c];
#pragma unroll
    for (int q = 0; q < 4; ++q) {
      const int r = r0 + rq + q * 4;
      const float4 h4 = *(const float4*)&hb[r * DD + d0];
      acc[q] += h4.x * m[0] + h4.y * m[1] + h4.z * m[2] + h4.w * m[3];
    }
  }
  const float b = bo[c];
#pragma unroll
  for (int q = 0; q < 4; ++q) {
    const int r = r0 + rq + q * 4;
    const int t = r >> 6, bb = r & 63;
    out[(bb * SS + t) * DOUTN + c] = acc[q] + b;
  }
}

// ---------------------------------------------------------------------------
extern "C" void kernel_launch(void* const* d_in, const int* in_sizes, int n_in,
                              void* d_out, int out_size, void* d_ws, size_t ws_size,
                              hipStream_t stream) {
  const float* x    = (const float*)d_in[0];
  const float* Wi   = (const float*)d_in[1];
  const float* bi   = (const float*)d_in[2];
  const float* P    = (const float*)d_in[3];
  const float* rotW = (const float*)d_in[4];
  const float* F    = (const float*)d_in[5];
  const float* G    = (const float*)d_in[6];
  const float* R    = (const float*)d_in[7];
  const float* Wo   = (const float*)d_in[8];
  const float* bo   = (const float*)d_in[9];
  float* out = (float*)d_out;
  float* ws  = (float*)d_ws;

  // workspace layout (floats): needs 19M floats = 76 MB
  float* W12  = ws;                    // 1M  : rotW[1] @ rotW[2]
  float* Ssym = W12 + (1 << 20);       // 1M  : R + R^T
  float* A2   = Ssym + (1 << 20);      // 64K : P @ Wi          [D, DIN]
  float* Mout = A2 + 65536;            // 64K : P @ Wo^T        [D, DOUT]
  float* cvec = Mout + 65536;          // 1K  : P @ bi
  float* ha   = ws + 3 * (1 << 20);    // 8M  : h ping  [S*B, D]
  float* hb   = ha + 8 * (1 << 20);    // 8M  : h pong

  const float* W0 = rotW;
  const float* W1 = rotW + (1 << 20);
  const float* W2 = rotW + 2 * (1 << 20);

  const dim3 blk(256);

  // ---- precompute (deterministic, every launch) ----
  k_symm<<<4096, blk, 0, stream>>>(R, Ssym);
  k_gemm_small<false><<<dim3(16, 16), blk, 0, stream>>>(W1, DD, W2, DD, W12, DD, DD, DD, DD);
  k_gemm_small<false><<<dim3(1, 16), blk, 0, stream>>>(P, DD, Wi, DINN, A2, DINN, DD, DINN, DD);
  k_gemm_small<true ><<<dim3(1, 16), blk, 0, stream>>>(P, DD, Wo, DD, Mout, DOUTN, DD, DOUTN, DD);
  k_matvec<<<4, blk, 0, stream>>>(P, bi, cvec);

  // ---- main pipeline over h: rows laid out [S, B] (r = t*64 + b) ----
  k_in<<<512, blk, 0, stream>>>(x, A2, cvec, ha);

  // rotor 0 forward (t-dependent roll folded into A/C indices)
  k_gemm_big<true , false, false><<<dim3(8, 64), blk, 0, stream>>>(ha, DD, W0, DD, hb, DD, DD);
  // rotors 1,2 precomposed
  k_gemm_big<false, false, false><<<dim3(8, 64), blk, 0, stream>>>(hb, DD, W12, DD, ha, DD, DD);
  // reversible blocks forward (in place on ha)
  for (int i = 0; i < 3; ++i) {
    k_gemm_big<false, false, true><<<dim3(4, 64), blk, 0, stream>>>(ha + 512, DD, F + i * 262144, 512, ha, DD, 512);
    k_gemm_big<false, false, true><<<dim3(4, 64), blk, 0, stream>>>(ha, DD, G + i * 262144, 512, ha + 512, DD, 512);
  }
  // reflector
  k_gemm_big<false, false, false><<<dim3(8, 64), blk, 0, stream>>>(ha, DD, Ssym, DD, hb, DD, DD);
  // reversible blocks reversed order (in place on hb)
  for (int i = 2; i >= 0; --i) {
    k_gemm_big<false, false, true><<<dim3(4, 64), blk, 0, stream>>>(hb + 512, DD, F + i * 262144, 512, hb, DD, 512);
    k_gemm_big<false, false, true><<<dim3(4, 64), blk, 0, stream>>>(hb, DD, G + i * 262144, 512, hb + 512, DD, 512);
  }
  // rotors inverse: (W1 W2)^T then rotor-0 inverse
  k_gemm_big<false, true , false><<<dim3(8, 64), blk, 0, stream>>>(hb, DD, W12, DD, ha, DD, DD);
  k_gemm_big<true , true , false><<<dim3(8, 64), blk, 0, stream>>>(ha, DD, W0, DD, hb, DD, DD);

  // plugboard-transpose + output projection (precomposed) + bias
  k_out<<<512, blk, 0, stream>>>(hb, Mout, bo, out);
}

// Round 3
// 2068.679 us; speedup vs baseline: 1.2585x; 1.2585x over previous
//
#include <hip/hip_runtime.h>
#include <math.h>

#define DD 1024
#define MM 8192   // B*S rows
#define SS 128
#define DINN 64
#define DOUTN 64

// direct global->LDS, 16B per lane; lds base must be wave-uniform
#define GLOAD_LDS(g, l) \
  __builtin_amdgcn_global_load_lds((const __attribute__((address_space(1))) void*)(g), \
                                   (__attribute__((address_space(3))) void*)(l), 16, 0, 0)

// ---------------------------------------------------------------------------
// Main GEMM.  Logical: Y[M=8192][N] = H[M][K] @ W[K][N], everything fp32.
// Storage: H^T-layout: A[k][m] (lda = MM), C written as Y^T: C[n(+shift)][m].
// W: [K][N] row-major (ldw).
// BM: m-rows per block (128 or 64). BN fixed 128. BK=32, double-buffered LDS
// staged entirely with global_load_lds (linear dest). One barrier per K-iter.
// SHIFT: store row = (n + SHIFT*t) & 1023 with t = m>>6  (rotor roll folded
// into the row index of the transposed store -> plain float4 stores).
// EPI: C = C_old + tanh(acc)  (reversible coupling).
// ---------------------------------------------------------------------------
template<int BM, bool EPI, int SHIFT>
__global__ __launch_bounds__(256)
void k_gemm(const float* __restrict__ A, const float* __restrict__ W,
            float* __restrict__ C, int ldw, int K) {
  constexpr int RT = BM / 16;            // acc rows per thread: 8 or 4
  constexpr int ACH = BM / 4;            // 16B chunks per A k-row
  constexpr int ACH_SH = (BM == 128) ? 5 : 4;
  __shared__ float sA[2][32 * BM];
  __shared__ float sW[2][32 * 128];

  // XCD swizzle: grid is always 512 blocks (%8==0). Each XCD gets a
  // contiguous m-range x all n-blocks -> A-panel read ~once from HBM.
  const int nwg = gridDim.x * gridDim.y;
  int wg = blockIdx.y * gridDim.x + blockIdx.x;
  wg = (wg & 7) * (nwg >> 3) + (wg >> 3);
  const int bx = wg % gridDim.x, by = wg / gridDim.x;

  const int col0 = bx * 128;             // n
  const int row0 = by * BM;              // m
  const int u = threadIdx.x;
  const int tx = u & 15;                 // m within tile
  const int ty = u >> 4;                 // n within tile (0..15)
  const int wave = u >> 6, lane = u & 63;

  float acc[RT][8];
#pragma unroll
  for (int i = 0; i < RT; ++i)
#pragma unroll
    for (int j = 0; j < 8; ++j) acc[i][j] = 0.f;

  const int niter = K >> 5;

  // ---- stage tile (k0) into buffer b ----
  auto stage = [&](int b, int k0) {
#pragma unroll
    for (int i = 0; i < BM / 32; ++i) {          // A: 32 k-rows x BM cols
      const int q = i * 256 + wave * 64 + lane;  // 16B-chunk index
      const int kr = q >> ACH_SH, mc = q & (ACH - 1);
      GLOAD_LDS(A + (size_t)(k0 + kr) * MM + row0 + mc * 4,
                &sA[b][(size_t)(i * 256 + wave * 64) * 4]);
    }
#pragma unroll
    for (int i = 0; i < 4; ++i) {                // W: 32 k-rows x 128 cols
      const int q = i * 256 + wave * 64 + lane;
      const int kr = q >> 5, nc = q & 31;
      GLOAD_LDS(W + (size_t)(k0 + kr) * ldw + col0 + nc * 4,
                &sW[b][(size_t)(i * 256 + wave * 64) * 4]);
    }
  };

  stage(0, 0);
  __syncthreads();

  int buf = 0;
  for (int it = 0; it < niter; ++it) {
    if (it + 1 < niter) stage(buf ^ 1, (it + 1) << 5);
    const float4* A4 = (const float4*)&sA[buf][0];
    const float4* W4 = (const float4*)&sW[buf][0];
#pragma unroll 8
    for (int kk = 0; kk < 32; ++kk) {
      const float4 b0 = W4[kk * 32 + ty];        // n cols ty*4..+3
      const float4 b1 = W4[kk * 32 + 16 + ty];   // n cols 64+ty*4..+3
      float bv[8] = {b0.x, b0.y, b0.z, b0.w, b1.x, b1.y, b1.z, b1.w};
      float av[RT];
      {
        const float4 a0 = A4[kk * (BM / 4) + tx];        // m tx*4..+3
        av[0] = a0.x; av[1] = a0.y; av[2] = a0.z; av[3] = a0.w;
        if (BM == 128) {
          const float4 a1 = A4[kk * 32 + 16 + tx];       // m 64+tx*4..+3
          av[4] = a1.x; av[5] = a1.y; av[6] = a1.z; av[7] = a1.w;
        }
      }
#pragma unroll
      for (int i = 0; i < RT; ++i)
#pragma unroll
        for (int j = 0; j < 8; ++j) acc[i][j] += av[i] * bv[j];
    }
    __syncthreads();
    buf ^= 1;
  }

  // ---- epilogue: coalesced float4 stores along m ----
#pragma unroll
  for (int h = 0; h < BM / 64; ++h) {
    const int m = row0 + h * 64 + tx * 4;
    const int t = m >> 6;                        // uniform per half
#pragma unroll
    for (int j = 0; j < 8; ++j) {
      const int n = col0 + ((j < 4) ? (ty * 4 + j) : (64 + ty * 4 + j - 4));
      int cr = n;
      if (SHIFT != 0) cr = (n + SHIFT * t + 2048) & (DD - 1);
      float* cp = C + (size_t)cr * MM + m;
      float v0 = acc[h * 4 + 0][j], v1 = acc[h * 4 + 1][j];
      float v2 = acc[h * 4 + 2][j], v3 = acc[h * 4 + 3][j];
      float4 v;
      if (EPI) {
        const float4 o = *(const float4*)cp;
        v.x = o.x + tanhf(v0); v.y = o.y + tanhf(v1);
        v.z = o.z + tanhf(v2); v.w = o.w + tanhf(v3);
      } else {
        v.x = v0; v.y = v1; v.z = v2; v.w = v3;
      }
      *(float4*)cp = v;
    }
  }
}

// ---------------------------------------------------------------------------
// input projection: h0[r][c] = sum_k A2[c][k]*x[b][t][k] + cvec[c],
// stored transposed & pre-rolled for rotor0: hT[(c - t) & 1023][r].
// grid (MM/64, DD/64); t uniform per block.
// ---------------------------------------------------------------------------
__global__ __launch_bounds__(256)
void k_in(const float* __restrict__ x, const float* __restrict__ A2,
          const float* __restrict__ cvec, float* __restrict__ hT) {
  const int r0 = blockIdx.x * 64;
  const int c0 = blockIdx.y * 64;
  const int t = r0 >> 6;
  __shared__ float xs[64][65];
  __shared__ float a2s[64][68];
  const int u = threadIdx.x;
#pragma unroll
  for (int i = 0; i < 4; ++i) {
    const int idx = i * 256 + u;
    const int rr = idx >> 4, kc = (idx & 15) * 4;
    const float4 v = *(const float4*)&x[(size_t)rr * (SS * DINN) + t * DINN + kc];
    xs[rr][kc] = v.x; xs[rr][kc + 1] = v.y; xs[rr][kc + 2] = v.z; xs[rr][kc + 3] = v.w;
    *(float4*)&a2s[rr][kc] = *(const float4*)&A2[(size_t)(c0 + rr) * DINN + kc];
  }
  __syncthreads();
  const int rr = u & 63;
  const int cg = (u >> 6) * 16;
  float acc[16];
#pragma unroll
  for (int cc = 0; cc < 16; ++cc) acc[cc] = 0.f;
  for (int k = 0; k < DINN; ++k) {
    const float xv = xs[rr][k];
#pragma unroll
    for (int cc = 0; cc < 16; ++cc) acc[cc] += xv * a2s[cg + cc][k];
  }
  const int r = r0 + rr;
#pragma unroll
  for (int cc = 0; cc < 16; ++cc) {
    const int c = c0 + cg + cc;
    const int cr = (c - t + DD) & (DD - 1);
    hT[(size_t)cr * MM + r] = acc[cc] + cvec[c];
  }
}

// ---------------------------------------------------------------------------
// output projection: out[b][t][c] = sum_d hT[d][r]*Mout[d][c] + bo[c]
// ---------------------------------------------------------------------------
__global__ __launch_bounds__(256)
void k_out(const float* __restrict__ hT, const float* __restrict__ Mout,
           const float* __restrict__ bo, float* __restrict__ out) {
  const int r0 = blockIdx.x * 64;
  const int u = threadIdx.x, rr = u & 63, cg = (u >> 6) * 16;
  __shared__ float ms[64][68];
  float acc[16];
#pragma unroll
  for (int cc = 0; cc < 16; ++cc) acc[cc] = 0.f;
  for (int d0 = 0; d0 < DD; d0 += 64) {
    __syncthreads();
#pragma unroll
    for (int i = 0; i < 4; ++i) {
      const int idx = i * 256 + u, dd = idx >> 4, kc = (idx & 15) * 4;
      *(float4*)&ms[dd][kc] = *(const float4*)&Mout[(size_t)(d0 + dd) * DOUTN + kc];
    }
    __syncthreads();
    for (int dd = 0; dd < 64; ++dd) {
      const float hv = hT[(size_t)(d0 + dd) * MM + r0 + rr];
#pragma unroll
      for (int cc = 0; cc < 16; ++cc) acc[cc] += hv * ms[dd][cg + cc];
    }
  }
  const int t = r0 >> 6, b = rr;
#pragma unroll
  for (int cc = 0; cc < 16; ++cc)
    out[((size_t)b * SS + t) * DOUTN + cg + cc] = acc[cc] + bo[cg + cc];
}

// ---------------------------------------------------------------------------
// precompute helpers
// ---------------------------------------------------------------------------
__global__ __launch_bounds__(256)
void k_symm(const float* __restrict__ R, float* __restrict__ S) {  // S = R + R^T
  const int i0 = blockIdx.y * 64, j0 = blockIdx.x * 64;
  __shared__ float tb[64][68];
  const int u = threadIdx.x;
#pragma unroll
  for (int it = 0; it < 4; ++it) {
    const int idx = it * 256 + u, rr = idx >> 4, cc = (idx & 15) * 4;
    *(float4*)&tb[rr][cc] = *(const float4*)&R[(size_t)(j0 + rr) * DD + i0 + cc];
  }
  __syncthreads();
#pragma unroll
  for (int it = 0; it < 4; ++it) {
    const int idx = it * 256 + u, rr = idx >> 4, cc = (idx & 15) * 4;
    float4 v = *(const float4*)&R[(size_t)(i0 + rr) * DD + j0 + cc];
    v.x += tb[cc + 0][rr]; v.y += tb[cc + 1][rr];
    v.z += tb[cc + 2][rr]; v.w += tb[cc + 3][rr];
    *(float4*)&S[(size_t)(i0 + rr) * DD + j0 + cc] = v;
  }
}

__global__ __launch_bounds__(256)
void k_transpose(const float* __restrict__ in, float* __restrict__ o) {  // o = in^T (1024x1024)
  const int i0 = blockIdx.y * 64, j0 = blockIdx.x * 64;
  __shared__ float tb[64][68];
  const int u = threadIdx.x;
#pragma unroll
  for (int it = 0; it < 4; ++it) {
    const int idx = it * 256 + u, rr = idx >> 4, cc = (idx & 15) * 4;
    *(float4*)&tb[rr][cc] = *(const float4*)&in[(size_t)(i0 + rr) * DD + j0 + cc];
  }
  __syncthreads();
#pragma unroll
  for (int it = 0; it < 4; ++it) {
    const int idx = it * 256 + u, rr = idx >> 4, cc = (idx & 15) * 4;
    float4 v;
    v.x = tb[cc + 0][rr]; v.y = tb[cc + 1][rr];
    v.z = tb[cc + 2][rr]; v.w = tb[cc + 3][rr];
    *(float4*)&o[(size_t)(j0 + rr) * DD + i0 + cc] = v;
  }
}

// split-K GEMM for W12 = W1 @ W2 (1024^3), 64x64 tiles, z = K quarter
__global__ __launch_bounds__(256)
void k_gemm_partk(const float* __restrict__ A, const float* __restrict__ W,
                  float* __restrict__ Cp) {
  const int z = blockIdx.z;
  const float* Ao = A + z * 256;
  const float* Wo = W + (size_t)z * 256 * DD;
  float* Co = Cp + (size_t)z * DD * DD;
  __shared__ float As[16][64];
  __shared__ float Ws[16][64];
  const int tx = threadIdx.x & 15, ty = threadIdx.x >> 4;
  const int row0 = blockIdx.y * 64, col0 = blockIdx.x * 64;
  float acc[4][4] = {};
  for (int k0 = 0; k0 < 256; k0 += 16) {
    const int u = threadIdx.x;
    {
      const int ar = u >> 2, ac4 = (u & 3) * 4;
#pragma unroll
      for (int j = 0; j < 4; ++j)
        As[ac4 + j][ar] = Ao[(size_t)(row0 + ar) * DD + k0 + ac4 + j];
    }
    {
      const int kk = u >> 4, c4 = (u & 15) * 4;
#pragma unroll
      for (int j = 0; j < 4; ++j)
        Ws[kk][c4 + j] = Wo[(size_t)(k0 + kk) * DD + col0 + c4 + j];
    }
    __syncthreads();
#pragma unroll
    for (int kk = 0; kk < 16; ++kk) {
      float a[4], b[4];
#pragma unroll
      for (int i = 0; i < 4; ++i) a[i] = As[kk][ty * 4 + i];
#pragma unroll
      for (int j = 0; j < 4; ++j) b[j] = Ws[kk][tx * 4 + j];
#pragma unroll
      for (int i = 0; i < 4; ++i)
#pragma unroll
        for (int j = 0; j < 4; ++j) acc[i][j] += a[i] * b[j];
    }
    __syncthreads();
  }
#pragma unroll
  for (int i = 0; i < 4; ++i)
#pragma unroll
    for (int j = 0; j < 4; ++j)
      Co[(size_t)(row0 + ty * 4 + i) * DD + col0 + tx * 4 + j] = acc[i][j];
}

__global__ __launch_bounds__(256)
void k_add4(const float* __restrict__ Wp, float* __restrict__ W12o) {
  const int idx = (blockIdx.x * 256 + threadIdx.x) * 4;
  float4 s = *(const float4*)&Wp[idx];
  const float4 s1 = *(const float4*)&Wp[(1 << 20) + idx];
  const float4 s2 = *(const float4*)&Wp[(2 << 20) + idx];
  const float4 s3 = *(const float4*)&Wp[(3 << 20) + idx];
  s.x += s1.x + s2.x + s3.x; s.y += s1.y + s2.y + s3.y;
  s.z += s1.z + s2.z + s3.z; s.w += s1.w + s2.w + s3.w;
  *(float4*)&W12o[idx] = s;
}

// A2 = P @ Wi  ([1024][64]); block = 4 rows x 64 cols
__global__ __launch_bounds__(256)
void k_pwi(const float* __restrict__ P, const float* __restrict__ Wi,
           float* __restrict__ A2) {
  const int m0 = blockIdx.x * 4;
  __shared__ float Ps[4][1024];
  const int u = threadIdx.x;
#pragma unroll
  for (int i = 0; i < 4; ++i) {
    const int idx = i * 256 + u, mi = idx >> 8, kc = (idx & 255) * 4;
    *(float4*)&Ps[mi][kc] = *(const float4*)&P[(size_t)(m0 + mi) * DD + kc];
  }
  __syncthreads();
  const int n = u & 63, mi = u >> 6;
  float acc = 0.f;
  for (int k = 0; k < DD; ++k) acc += Ps[mi][k] * Wi[(size_t)k * DINN + n];
  A2[(size_t)(m0 + mi) * DINN + n] = acc;
}

// Mout[d][c] = sum_k P[d][k] * Wo[c][k]
__global__ __launch_bounds__(256)
void k_pwo(const float* __restrict__ P, const float* __restrict__ Wo_,
           float* __restrict__ Mo) {
  const int d0 = blockIdx.x * 4;
  __shared__ float Ps[4][1024];
  __shared__ float ws[64][65];
  const int u = threadIdx.x;
#pragma unroll
  for (int i = 0; i < 4; ++i) {
    const int idx = i * 256 + u, mi = idx >> 8, kc = (idx & 255) * 4;
    *(float4*)&Ps[mi][kc] = *(const float4*)&P[(size_t)(d0 + mi) * DD + kc];
  }
  const int c = u & 63, di = u >> 6;
  float acc = 0.f;
  for (int k0 = 0; k0 < DD; k0 += 64) {
    __syncthreads();
#pragma unroll
    for (int i = 0; i < 4; ++i) {
      const int idx = i * 256 + u, cc = idx >> 4, kc = (idx & 15) * 4;
      const float4 v = *(const float4*)&Wo_[(size_t)cc * DD + k0 + kc];
      ws[cc][kc] = v.x; ws[cc][kc + 1] = v.y; ws[cc][kc + 2] = v.z; ws[cc][kc + 3] = v.w;
    }
    __syncthreads();
    for (int kk = 0; kk < 64; ++kk) acc += Ps[di][k0 + kk] * ws[c][kk];
  }
  Mo[(size_t)(d0 + di) * DOUTN + c] = acc;
}

// cvec = P @ bi ; wave per row
__global__ __launch_bounds__(256)
void k_matvec(const float* __restrict__ P, const float* __restrict__ b,
              float* __restrict__ c) {
  const int row = blockIdx.x * 4 + (threadIdx.x >> 6);
  const int l = threadIdx.x & 63;
  float s = 0.f;
  for (int k = l; k < DD; k += 64) s += P[(size_t)row * DD + k] * b[k];
  for (int o = 32; o; o >>= 1) s += __shfl_down(s, o, 64);
  if (l == 0) c[row] = s;
}

// ---------------------------------------------------------------------------
extern "C" void kernel_launch(void* const* d_in, const int* in_sizes, int n_in,
                              void* d_out, int out_size, void* d_ws, size_t ws_size,
                              hipStream_t stream) {
  (void)in_sizes; (void)n_in; (void)out_size; (void)ws_size;
  const float* x    = (const float*)d_in[0];
  const float* Wi   = (const float*)d_in[1];
  const float* bi   = (const float*)d_in[2];
  const float* P    = (const float*)d_in[3];
  const float* rotW = (const float*)d_in[4];
  const float* F    = (const float*)d_in[5];
  const float* G    = (const float*)d_in[6];
  const float* R    = (const float*)d_in[7];
  const float* Wo   = (const float*)d_in[8];
  const float* bo   = (const float*)d_in[9];
  float* out = (float*)d_out;
  float* ws  = (float*)d_ws;

  // workspace (floats), total ~18.14M floats = 72.6 MB:
  float* ha    = ws;                        // 8M : h^T ping [1024][8192]
  float* hb    = ws + (8u << 20);           // 8M : h^T pong (Wpart aliases first 4M)
  float* slot1 = ws + (16u << 20);          // 1M : W12, later W0^T
  float* slot2 = slot1 + (1u << 20);        // 1M : Ssym, later W12^T
  float* A2    = slot2 + (1u << 20);        // 64K
  float* Mout  = A2 + 65536;                // 64K
  float* cvec  = Mout + 65536;              // 1K
  float* Wpart = hb;                        // 4M alias (dead before hb written)

  const float* W0 = rotW;
  const float* W1 = rotW + (1u << 20);
  const float* W2 = rotW + (2u << 20);

  const dim3 blk(256);

  // ---- precompute ----
  k_symm      <<<dim3(16, 16), blk, 0, stream>>>(R, slot2);           // Ssym
  k_gemm_partk<<<dim3(16, 16, 4), blk, 0, stream>>>(W1, W2, Wpart);
  k_add4      <<<dim3(1024), blk, 0, stream>>>(Wpart, slot1);         // W12
  k_pwi       <<<dim3(256), blk, 0, stream>>>(P, Wi, A2);
  k_pwo       <<<dim3(256), blk, 0, stream>>>(P, Wo, Mout);
  k_matvec    <<<dim3(256), blk, 0, stream>>>(P, bi, cvec);

  // ---- main pipeline (h stored transposed [1024][8192]) ----
  k_in<<<dim3(128, 16), blk, 0, stream>>>(x, A2, cvec, ha);           // pre-rolled (-t)

  // rotor 0 fwd: A pre-rolled, store rolled back (+t)
  k_gemm<128, false, +1><<<dim3(8, 64), blk, 0, stream>>>(ha, W0, hb, DD, DD);
  // rotors 1,2 precomposed
  k_gemm<128, false, 0><<<dim3(8, 64), blk, 0, stream>>>(hb, slot1, ha, DD, DD);
  // reversible blocks fwd (in place on ha; h2 = rows 512.., y1 = rows 0..)
  for (int i = 0; i < 3; ++i) {
    k_gemm<64, true, 0><<<dim3(4, 128), blk, 0, stream>>>(ha + (size_t)512 * MM, F + (size_t)i * 262144, ha, 512, 512);
    k_gemm<64, true, 0><<<dim3(4, 128), blk, 0, stream>>>(ha, G + (size_t)i * 262144, ha + (size_t)512 * MM, 512, 512);
  }
  // reflector
  k_gemm<128, false, 0><<<dim3(8, 64), blk, 0, stream>>>(ha, slot2, hb, DD, DD);
  // slot2 (Ssym) now dead -> put W12^T there
  k_transpose<<<dim3(16, 16), blk, 0, stream>>>(slot1, slot2);
  // reversible blocks reversed order (in place on hb)
  for (int i = 2; i >= 0; --i) {
    k_gemm<64, true, 0><<<dim3(4, 128), blk, 0, stream>>>(hb + (size_t)512 * MM, F + (size_t)i * 262144, hb, 512, 512);
    k_gemm<64, true, 0><<<dim3(4, 128), blk, 0, stream>>>(hb, G + (size_t)i * 262144, hb + (size_t)512 * MM, 512, 512);
  }
  // rotors inverse: W12^T (store pre-rolled -t for rotor0-inv)
  k_gemm<128, false, -1><<<dim3(8, 64), blk, 0, stream>>>(hb, slot2, ha, DD, DD);
  // slot1 (W12) now dead -> put W0^T there
  k_transpose<<<dim3(16, 16), blk, 0, stream>>>(W0, slot1);
  // rotor 0 inverse: store rolled back (+t) -> linear
  k_gemm<128, false, +1><<<dim3(8, 64), blk, 0, stream>>>(ha, slot1, hb, DD, DD);

  // output projection
  k_out<<<dim3(128), blk, 0, stream>>>(hb, Mout, bo, out);
}

// Round 4
// 872.932 us; speedup vs baseline: 2.9824x; 2.3698x over previous
//
#include <hip/hip_runtime.h>
#include <math.h>

#define DD 1024
#define MM 8192   // B*S rows
#define SS 128
#define DINN 64
#define DOUTN 64

typedef _Float16 f16;
typedef _Float16 f16x8 __attribute__((ext_vector_type(8)));
typedef _Float16 f16x4 __attribute__((ext_vector_type(4)));
typedef float    f32x4 __attribute__((ext_vector_type(4)));

// direct global->LDS, 16B per lane; LDS base must be wave-uniform
#define GLOAD_LDS(g, l) \
  __builtin_amdgcn_global_load_lds((const __attribute__((address_space(1))) void*)(g), \
                                   (__attribute__((address_space(3))) void*)(l), 16, 0, 0)

// split helpers: store hi' = f16(y)*64, lo' = f16((y - hi)*64); y = hi'/64 + lo'/4096.
__device__ __forceinline__ void split_store(float y, f16* __restrict__ hp, f16* __restrict__ lp, size_t idx) {
  f16 h = (f16)y;
  hp[idx] = h * (f16)64.0f;
  lp[idx] = (f16)((y - (float)h) * 64.0f);
}
__device__ __forceinline__ float join_load(const f16* __restrict__ hp, const f16* __restrict__ lp, size_t idx) {
  return (float)hp[idx] * 0.015625f + (float)lp[idx] * 0.000244140625f;
}

// ---------------------------------------------------------------------------
// Split-f16 MFMA GEMM.  Logical: Y[M][N] = H[M][K] @ W^T-ish, fp32-accurate via
//   Y = (Ahi+Alo/64)(Bhi+Blo/64)/4096 with terms hihi + hilo + lohi (lolo ~2^-22 dropped).
// A planes: [M][K] f16 (row stride lda), pre-scaled x64 two-term split.
// B planes: [N][K] f16 (row stride ldb)  == weight stored transposed.
// C planes: [M][ldc] f16 (hi x64, lo x64-resid).
// BM in {128, 64}; BN = 128; BK = 32; 256 threads = 4 waves.
//   BM=128: wave tile 64x64 (MT=4); BM=64: wave tile 32x64 (MT=2).
// mfma_f32_16x16x32_f16; LDS per-plane tiles [rows][32] f16 (64B rows),
// 16B-chunk XOR swizzle kc^=(row&3) -> bank-balanced b128 fragment reads.
// SHIFT: store col = (n + SHIFT*(m>>6)) & 1023 (rotor roll folded into store).
// EPI:  y = y_old + tanh(acc/4096) (reversible coupling, in-place-safe by col split).
// ---------------------------------------------------------------------------
template<int BM, bool EPI, int SHIFT>
__global__ __launch_bounds__(256)
void k_gemm16(const f16* __restrict__ Ahi, const f16* __restrict__ Alo, int lda,
              const f16* __restrict__ Bhi, const f16* __restrict__ Blo, int ldb,
              f16* __restrict__ Chi, f16* __restrict__ Clo, int ldc, int K) {
  constexpr int MT = BM / 32;      // 16x16 m-tiles per wave
  constexpr int AI = BM / 64;      // A staging iterations (chunks = BM*4)
  __shared__ f16 sA[2][2][BM * 32];
  __shared__ f16 sB[2][2][128 * 32];

  // XCD-aware swizzle (nwg % 8 == 0 for all our grids)
  const int nwg = gridDim.x * gridDim.y;
  int wg = blockIdx.y * gridDim.x + blockIdx.x;
  wg = (wg & 7) * (nwg >> 3) + (wg >> 3);
  const int bx = wg % gridDim.x, by = wg / gridDim.x;

  const int col0 = bx * 128, row0 = by * BM;
  const int u = threadIdx.x, lane = u & 63, wv = u >> 6;
  const int mh = (wv >> 1) * (BM >> 1);   // wave m-offset
  const int nh = (wv & 1) * 64;           // wave n-offset

  // staging source offsets (pre-swizzled so linear LDS dest => swizzled layout)
  unsigned aoff[AI], boff[2];
  unsigned dstA[AI], dstB[2];
#pragma unroll
  for (int i = 0; i < AI; ++i) {
    const int P = i * 256 + u;
    const int row = P >> 2, kc = (P & 3) ^ (row & 3);
    aoff[i] = (unsigned)(row0 + row) * lda + kc * 8;
    dstA[i] = (i * 256 + wv * 64) * 8;     // wave-uniform (f16 elems)
  }
#pragma unroll
  for (int i = 0; i < 2; ++i) {
    const int P = i * 256 + u;
    const int row = P >> 2, kc = (P & 3) ^ (row & 3);
    boff[i] = (unsigned)(col0 + row) * ldb + kc * 8;
    dstB[i] = (i * 256 + wv * 64) * 8;
  }

  // fragment read offset within a plane block (row&3 == lane&3 since tile bases %4==0)
  const int frag = (lane & 15) * 32 + (((lane >> 4) ^ (lane & 3)) * 8);

  f32x4 acc[MT][4];
#pragma unroll
  for (int mt = 0; mt < MT; ++mt)
#pragma unroll
    for (int nt = 0; nt < 4; ++nt) acc[mt][nt] = (f32x4){0.f, 0.f, 0.f, 0.f};

  auto stage = [&](int b, int k0) {
#pragma unroll
    for (int i = 0; i < AI; ++i) {
      GLOAD_LDS(Ahi + aoff[i] + k0, &sA[b][0][dstA[i]]);
      GLOAD_LDS(Alo + aoff[i] + k0, &sA[b][1][dstA[i]]);
    }
#pragma unroll
    for (int i = 0; i < 2; ++i) {
      GLOAD_LDS(Bhi + boff[i] + k0, &sB[b][0][dstB[i]]);
      GLOAD_LDS(Blo + boff[i] + k0, &sB[b][1][dstB[i]]);
    }
  };

  const int niter = K >> 5;
  stage(0, 0);
  __syncthreads();

  int buf = 0;
  for (int it = 0; it < niter; ++it) {
    if (it + 1 < niter) stage(buf ^ 1, (it + 1) << 5);
    f16x8 aH[MT], aL[MT], bH[4], bL[4];
#pragma unroll
    for (int mt = 0; mt < MT; ++mt) {
      aH[mt] = *(const f16x8*)&sA[buf][0][(mh + mt * 16) * 32 + frag];
      aL[mt] = *(const f16x8*)&sA[buf][1][(mh + mt * 16) * 32 + frag];
    }
#pragma unroll
    for (int nt = 0; nt < 4; ++nt) {
      bH[nt] = *(const f16x8*)&sB[buf][0][(nh + nt * 16) * 32 + frag];
      bL[nt] = *(const f16x8*)&sB[buf][1][(nh + nt * 16) * 32 + frag];
    }
#pragma unroll
    for (int mt = 0; mt < MT; ++mt)
#pragma unroll
      for (int nt = 0; nt < 4; ++nt) {
        acc[mt][nt] = __builtin_amdgcn_mfma_f32_16x16x32_f16(aH[mt], bH[nt], acc[mt][nt], 0, 0, 0);
        acc[mt][nt] = __builtin_amdgcn_mfma_f32_16x16x32_f16(aH[mt], bL[nt], acc[mt][nt], 0, 0, 0);
        acc[mt][nt] = __builtin_amdgcn_mfma_f32_16x16x32_f16(aL[mt], bH[nt], acc[mt][nt], 0, 0, 0);
      }
    __syncthreads();
    buf ^= 1;
  }

  // epilogue: y = acc/4096; split-store (optional shift / reversible add)
#pragma unroll
  for (int mt = 0; mt < MT; ++mt)
#pragma unroll
    for (int nt = 0; nt < 4; ++nt) {
      const f32x4 a = acc[mt][nt];
      const int n_base = col0 + nh + nt * 16 + (lane & 15);
#pragma unroll
      for (int r = 0; r < 4; ++r) {
        const int m = row0 + mh + mt * 16 + ((lane >> 4) << 2) + r;
        int n = n_base;
        if (SHIFT != 0) n = (n + SHIFT * (m >> 6) + 2048) & (DD - 1);
        const size_t idx = (size_t)m * ldc + n;
        float y = a[r] * 0.000244140625f;
        if (EPI) y = join_load(Chi, Clo, idx) + tanhf(y);
        split_store(y, Chi, Clo, idx);
      }
    }
}

// ---------------------------------------------------------------------------
// input projection: y[r][c] = sum_k A2[c][k]*x[b][t][k] + cvec[c], r = t*64+b,
// split-stored pre-rolled for rotor0: h[r][(c - t) & 1023].
// ---------------------------------------------------------------------------
__global__ __launch_bounds__(256)
void k_in16(const float* __restrict__ x, const float* __restrict__ A2,
            const float* __restrict__ cvec, f16* __restrict__ hH, f16* __restrict__ hL) {
  const int r0 = blockIdx.x * 64;
  const int c0 = blockIdx.y * 64;
  const int t = r0 >> 6;
  __shared__ float xs[64][65];
  __shared__ float a2s[64][68];
  const int u = threadIdx.x;
#pragma unroll
  for (int i = 0; i < 4; ++i) {
    const int idx = i * 256 + u;
    const int rr = idx >> 4, kc = (idx & 15) * 4;
    const float4 v = *(const float4*)&x[(size_t)rr * (SS * DINN) + t * DINN + kc];
    xs[rr][kc] = v.x; xs[rr][kc + 1] = v.y; xs[rr][kc + 2] = v.z; xs[rr][kc + 3] = v.w;
    *(float4*)&a2s[rr][kc] = *(const float4*)&A2[(size_t)(c0 + rr) * DINN + kc];
  }
  __syncthreads();
  const int rr = u & 63;
  const int cg = (u >> 6) * 16;
  float acc[16];
#pragma unroll
  for (int cc = 0; cc < 16; ++cc) acc[cc] = 0.f;
  for (int k = 0; k < DINN; ++k) {
    const float xv = xs[rr][k];
#pragma unroll
    for (int cc = 0; cc < 16; ++cc) acc[cc] += xv * a2s[cg + cc][k];
  }
  const int r = r0 + rr;
#pragma unroll
  for (int cc = 0; cc < 16; ++cc) {
    const int c = c0 + cg + cc;
    const int cr = (c - t + DD) & (DD - 1);
    split_store(acc[cc] + cvec[c], hH, hL, (size_t)r * DD + cr);
  }
}

// ---------------------------------------------------------------------------
// output projection: out[b][t][c] = sum_d h[r][d]*Mout[d][c] + bo[c]
// 16 rows/block; h rows joined to fp32 in LDS once, Mout staged per 64-chunk.
// ---------------------------------------------------------------------------
__global__ __launch_bounds__(256)
void k_out16(const f16* __restrict__ hH, const f16* __restrict__ hL,
             const float* __restrict__ Mout, const float* __restrict__ bo,
             float* __restrict__ out) {
  const int r0 = blockIdx.x * 16;
  __shared__ float ylds[16][DD];
  __shared__ float ms[64][68];
  const int u = threadIdx.x;
#pragma unroll
  for (int i = 0; i < 8; ++i) {          // 2048 chunks of 8 f16
    const int C = i * 256 + u;
    const int row = C >> 7, ch = C & 127;
    const size_t g = (size_t)(r0 + row) * DD + ch * 8;
    const f16x8 vh = *(const f16x8*)&hH[g];
    const f16x8 vl = *(const f16x8*)&hL[g];
#pragma unroll
    for (int j = 0; j < 8; ++j)
      ylds[row][ch * 8 + j] = (float)vh[j] * 0.015625f + (float)vl[j] * 0.000244140625f;
  }
  const int c = u & 63, rq = u >> 6;
  float acc[4] = {0.f, 0.f, 0.f, 0.f};
  for (int d0 = 0; d0 < DD; d0 += 64) {
    __syncthreads();
#pragma unroll
    for (int i = 0; i < 4; ++i) {
      const int idx = i * 256 + u, dd = idx >> 4, kc = (idx & 15) * 4;
      *(float4*)&ms[dd][kc] = *(const float4*)&Mout[(size_t)(d0 + dd) * DOUTN + kc];
    }
    __syncthreads();
    for (int dd = 0; dd < 64; ++dd) {
      const float mv = ms[dd][c];
#pragma unroll
      for (int q = 0; q < 4; ++q) acc[q] += ylds[rq + q * 4][d0 + dd] * mv;
    }
  }
  const int t = r0 >> 6;
#pragma unroll
  for (int q = 0; q < 4; ++q) {
    const int r = r0 + rq + q * 4;
    const int b = r & 63;
    out[((size_t)b * SS + t) * DOUTN + c] = acc[q] + bo[c];
  }
}

// ---------------------------------------------------------------------------
// precompute: splits / transposes
// ---------------------------------------------------------------------------
__global__ __launch_bounds__(256)
void k_split(const float* __restrict__ src, f16* __restrict__ hi, f16* __restrict__ lo) {
  const int i = blockIdx.x * 256 + threadIdx.x;
  const float4 v = ((const float4*)src)[i];
  f16x4 h4, l4;
  const float vv[4] = {v.x, v.y, v.z, v.w};
#pragma unroll
  for (int j = 0; j < 4; ++j) {
    f16 h = (f16)vv[j];
    h4[j] = h * (f16)64.0f;
    l4[j] = (f16)((vv[j] - (float)h) * 64.0f);
  }
  ((f16x4*)hi)[i] = h4;
  ((f16x4*)lo)[i] = l4;
}

// transpose + split: src fp32 [dim][dim] (z-batched) -> planes [dim][dim] = src^T
__global__ __launch_bounds__(256)
void k_splitT(const float* __restrict__ src, f16* __restrict__ hi, f16* __restrict__ lo, int dim) {
  const size_t zo = (size_t)blockIdx.z * dim * dim;
  src += zo; hi += zo; lo += zo;
  const int i0 = blockIdx.y * 64, j0 = blockIdx.x * 64;
  __shared__ float tb[64][68];
  const int u = threadIdx.x;
#pragma unroll
  for (int it = 0; it < 4; ++it) {
    const int idx = it * 256 + u, rr = idx >> 4, cc = (idx & 15) * 4;
    *(float4*)&tb[rr][cc] = *(const float4*)&src[(size_t)(i0 + rr) * dim + j0 + cc];
  }
  __syncthreads();
#pragma unroll
  for (int it = 0; it < 4; ++it) {
    const int idx = it * 256 + u, rr = idx >> 4, cc = (idx & 15) * 4;
    f16x4 h4, l4;
#pragma unroll
    for (int j = 0; j < 4; ++j) {
      const float y = tb[cc + j][rr];
      f16 h = (f16)y;
      h4[j] = h * (f16)64.0f;
      l4[j] = (f16)((y - (float)h) * 64.0f);
    }
    const size_t o = (size_t)(j0 + rr) * dim + i0 + cc;
    *(f16x4*)&hi[o] = h4;
    *(f16x4*)&lo[o] = l4;
  }
}

// S = R + R^T, split-stored (symmetric => [n][k] fine)
__global__ __launch_bounds__(256)
void k_symm_split(const float* __restrict__ R, f16* __restrict__ hi, f16* __restrict__ lo) {
  const int i0 = blockIdx.y * 64, j0 = blockIdx.x * 64;
  __shared__ float tb[64][68];
  const int u = threadIdx.x;
#pragma unroll
  for (int it = 0; it < 4; ++it) {
    const int idx = it * 256 + u, rr = idx >> 4, cc = (idx & 15) * 4;
    *(float4*)&tb[rr][cc] = *(const float4*)&R[(size_t)(j0 + rr) * DD + i0 + cc];
  }
  __syncthreads();
#pragma unroll
  for (int it = 0; it < 4; ++it) {
    const int idx = it * 256 + u, rr = idx >> 4, cc = (idx & 15) * 4;
    const float4 v = *(const float4*)&R[(size_t)(i0 + rr) * DD + j0 + cc];
    const float vv[4] = {v.x + tb[cc + 0][rr], v.y + tb[cc + 1][rr],
                         v.z + tb[cc + 2][rr], v.w + tb[cc + 3][rr]};
    f16x4 h4, l4;
#pragma unroll
    for (int j = 0; j < 4; ++j) {
      f16 h = (f16)vv[j];
      h4[j] = h * (f16)64.0f;
      l4[j] = (f16)((vv[j] - (float)h) * 64.0f);
    }
    const size_t o = (size_t)(i0 + rr) * DD + j0 + cc;
    *(f16x4*)&hi[o] = h4;
    *(f16x4*)&lo[o] = l4;
  }
}

// f16 plane transpose (for B12t from B12)
__global__ __launch_bounds__(256)
void k_tr16(const f16* __restrict__ in, f16* __restrict__ o, int dim) {
  const int i0 = blockIdx.y * 64, j0 = blockIdx.x * 64;
  __shared__ f16 tb[64][72];
  const int u = threadIdx.x;
#pragma unroll
  for (int it = 0; it < 2; ++it) {
    const int C = it * 256 + u, row = C >> 3, ch = C & 7;
    *(f16x8*)&tb[row][ch * 8] = *(const f16x8*)&in[(size_t)(i0 + row) * dim + j0 + ch * 8];
  }
  __syncthreads();
#pragma unroll
  for (int it = 0; it < 2; ++it) {
    const int C = it * 256 + u, row = C >> 3, ch = C & 7;
    f16x8 v;
#pragma unroll
    for (int j = 0; j < 8; ++j) v[j] = tb[ch * 8 + j][row];
    *(f16x8*)&o[(size_t)(j0 + row) * dim + i0 + ch * 8] = v;
  }
}

// A2 = P @ Wi  ([1024][64])
__global__ __launch_bounds__(256)
void k_pwi(const float* __restrict__ P, const float* __restrict__ Wi,
           float* __restrict__ A2) {
  const int m0 = blockIdx.x * 4;
  __shared__ float Ps[4][1024];
  const int u = threadIdx.x;
#pragma unroll
  for (int i = 0; i < 4; ++i) {
    const int idx = i * 256 + u, mi = idx >> 8, kc = (idx & 255) * 4;
    *(float4*)&Ps[mi][kc] = *(const float4*)&P[(size_t)(m0 + mi) * DD + kc];
  }
  __syncthreads();
  const int n = u & 63, mi = u >> 6;
  float acc = 0.f;
  for (int k = 0; k < DD; ++k) acc += Ps[mi][k] * Wi[(size_t)k * DINN + n];
  A2[(size_t)(m0 + mi) * DINN + n] = acc;
}

// Mout[d][c] = sum_k P[d][k] * Wo[c][k]
__global__ __launch_bounds__(256)
void k_pwo(const float* __restrict__ P, const float* __restrict__ Wo_,
           float* __restrict__ Mo) {
  const int d0 = blockIdx.x * 4;
  __shared__ float Ps[4][1024];
  __shared__ float ws[64][65];
  const int u = threadIdx.x;
#pragma unroll
  for (int i = 0; i < 4; ++i) {
    const int idx = i * 256 + u, mi = idx >> 8, kc = (idx & 255) * 4;
    *(float4*)&Ps[mi][kc] = *(const float4*)&P[(size_t)(d0 + mi) * DD + kc];
  }
  const int c = u & 63, di = u >> 6;
  float acc = 0.f;
  for (int k0 = 0; k0 < DD; k0 += 64) {
    __syncthreads();
#pragma unroll
    for (int i = 0; i < 4; ++i) {
      const int idx = i * 256 + u, cc = idx >> 4, kc = (idx & 15) * 4;
      const float4 v = *(const float4*)&Wo_[(size_t)cc * DD + k0 + kc];
      ws[cc][kc] = v.x; ws[cc][kc + 1] = v.y; ws[cc][kc + 2] = v.z; ws[cc][kc + 3] = v.w;
    }
    __syncthreads();
    for (int kk = 0; kk < 64; ++kk) acc += Ps[di][k0 + kk] * ws[c][kk];
  }
  Mo[(size_t)(d0 + di) * DOUTN + c] = acc;
}

// cvec = P @ bi ; wave per row
__global__ __launch_bounds__(256)
void k_matvec(const float* __restrict__ P, const float* __restrict__ b,
              float* __restrict__ c) {
  const int row = blockIdx.x * 4 + (threadIdx.x >> 6);
  const int l = threadIdx.x & 63;
  float s = 0.f;
  for (int k = l; k < DD; k += 64) s += P[(size_t)row * DD + k] * b[k];
  for (int o = 32; o; o >>= 1) s += __shfl_down(s, o, 64);
  if (l == 0) c[row] = s;
}

// ---------------------------------------------------------------------------
extern "C" void kernel_launch(void* const* d_in, const int* in_sizes, int n_in,
                              void* d_out, int out_size, void* d_ws, size_t ws_size,
                              hipStream_t stream) {
  (void)in_sizes; (void)n_in; (void)out_size; (void)ws_size;
  const float* x    = (const float*)d_in[0];
  const float* Wi   = (const float*)d_in[1];
  const float* bi   = (const float*)d_in[2];
  const float* P    = (const float*)d_in[3];
  const float* rotW = (const float*)d_in[4];
  const float* F    = (const float*)d_in[5];
  const float* G    = (const float*)d_in[6];
  const float* R    = (const float*)d_in[7];
  const float* Wo   = (const float*)d_in[8];
  const float* bo   = (const float*)d_in[9];
  float* out = (float*)d_out;
  char* w = (char*)d_ws;

  constexpr size_t MB = 1u << 20;
  // h planes (f16, [8192][1024], hi scaled x64, lo = resid x64)
  f16* haH = (f16*)(w + 0 * MB);
  f16* haL = (f16*)(w + 16 * MB);
  f16* hbH = (f16*)(w + 32 * MB);
  f16* hbL = (f16*)(w + 48 * MB);
  // weight planes ([n][k] layout)
  f16* B0tH = (f16*)(w + 64 * MB); f16* B0tL = (f16*)(w + 66 * MB);   // W0^T
  f16* B12tH= (f16*)(w + 68 * MB); f16* B12tL= (f16*)(w + 70 * MB);   // W12^T
  f16* BssH = (f16*)(w + 72 * MB); f16* BssL = (f16*)(w + 74 * MB);   // R+R^T
  f16* B12H = (f16*)(w + 76 * MB); f16* B12L = (f16*)(w + 78 * MB);   // W12
  f16* B0H  = (f16*)(w + 80 * MB); f16* B0L  = (f16*)(w + 82 * MB);   // W0
  f16* BFH  = (f16*)(w + 84 * MB); f16* BFL  = (f16*)(w + 85 * MB + 512 * 1024); // F^T x3
  f16* BGH  = (f16*)(w + 87 * MB); f16* BGL  = (f16*)(w + 88 * MB + 512 * 1024); // G^T x3
  // fp32 small
  float* A2   = (float*)(w + 90 * MB);
  float* Mout = (float*)(w + 90 * MB + 256 * 1024);
  float* cvec = (float*)(w + 90 * MB + 512 * 1024);
  // temp W1/W2 split planes alias hb region (dead until first GEMM writes hb)
  f16* W1sH = (f16*)(w + 32 * MB); f16* W1sL = (f16*)(w + 34 * MB);
  f16* W2tH = (f16*)(w + 36 * MB); f16* W2tL = (f16*)(w + 38 * MB);

  const float* W0 = rotW;
  const float* W1 = rotW + (1u << 20);
  const float* W2 = rotW + (2u << 20);

  const dim3 blk(256);
  const size_t FGQ = (size_t)512 * 512;

  // ---- precompute: weight splits ----
  k_split     <<<dim3(1024), blk, 0, stream>>>(W1, W1sH, W1sL);                 // W1 [m][k]
  k_splitT    <<<dim3(16, 16), blk, 0, stream>>>(W2, W2tH, W2tL, DD);           // W2^T [n][k]
  // W12 = W1 @ W2 in split-f16 -> B12 planes ([m][n] = W12 as-is = [n][k] for inverse mult)
  k_gemm16<128, false, 0><<<dim3(8, 8), blk, 0, stream>>>(W1sH, W1sL, DD, W2tH, W2tL, DD, B12H, B12L, DD, DD);
  k_tr16      <<<dim3(16, 16), blk, 0, stream>>>(B12H, B12tH, DD);              // W12^T planes
  k_tr16      <<<dim3(16, 16), blk, 0, stream>>>(B12L, B12tL, DD);
  k_symm_split<<<dim3(16, 16), blk, 0, stream>>>(R, BssH, BssL);
  k_splitT    <<<dim3(16, 16), blk, 0, stream>>>(W0, B0tH, B0tL, DD);           // W0^T
  k_split     <<<dim3(1024), blk, 0, stream>>>(W0, B0H, B0L);                   // W0 as-is
  k_splitT    <<<dim3(8, 8, 3), blk, 0, stream>>>(F, BFH, BFL, 512);            // F_i^T
  k_splitT    <<<dim3(8, 8, 3), blk, 0, stream>>>(G, BGH, BGL, 512);            // G_i^T
  k_pwi       <<<dim3(256), blk, 0, stream>>>(P, Wi, A2);
  k_pwo       <<<dim3(256), blk, 0, stream>>>(P, Wo, Mout);
  k_matvec    <<<dim3(256), blk, 0, stream>>>(P, bi, cvec);

  // ---- main pipeline ----
  k_in16<<<dim3(128, 16), blk, 0, stream>>>(x, A2, cvec, haH, haL);             // pre-rolled (-t)

  // rotor 0 fwd (A pre-rolled, store +t)
  k_gemm16<128, false, +1><<<dim3(8, 64), blk, 0, stream>>>(haH, haL, DD, B0tH, B0tL, DD, hbH, hbL, DD, DD);
  // rotors 1,2 precomposed
  k_gemm16<128, false, 0><<<dim3(8, 64), blk, 0, stream>>>(hbH, hbL, DD, B12tH, B12tL, DD, haH, haL, DD, DD);
  // reversible blocks fwd (in place on ha; h2 = cols 512.., y1 = cols 0..)
  for (int i = 0; i < 3; ++i) {
    k_gemm16<64, true, 0><<<dim3(4, 128), blk, 0, stream>>>(haH + 512, haL + 512, DD, BFH + i * FGQ, BFL + i * FGQ, 512, haH, haL, DD, 512);
    k_gemm16<64, true, 0><<<dim3(4, 128), blk, 0, stream>>>(haH, haL, DD, BGH + i * FGQ, BGL + i * FGQ, 512, haH + 512, haL + 512, DD, 512);
  }
  // reflector
  k_gemm16<128, false, 0><<<dim3(8, 64), blk, 0, stream>>>(haH, haL, DD, BssH, BssL, DD, hbH, hbL, DD, DD);
  // reversible blocks reversed (in place on hb)
  for (int i = 2; i >= 0; --i) {
    k_gemm16<64, true, 0><<<dim3(4, 128), blk, 0, stream>>>(hbH + 512, hbL + 512, DD, BFH + i * FGQ, BFL + i * FGQ, 512, hbH, hbL, DD, 512);
    k_gemm16<64, true, 0><<<dim3(4, 128), blk, 0, stream>>>(hbH, hbL, DD, BGH + i * FGQ, BGL + i * FGQ, 512, hbH + 512, hbL + 512, DD, 512);
  }
  // rotors inverse: W12^T-mult (B = W12 as-is), store pre-rolled (-t)
  k_gemm16<128, false, -1><<<dim3(8, 64), blk, 0, stream>>>(hbH, hbL, DD, B12H, B12L, DD, haH, haL, DD, DD);
  // rotor 0 inverse: W0^T-mult (B = W0 as-is), store +t -> linear
  k_gemm16<128, false, +1><<<dim3(8, 64), blk, 0, stream>>>(haH, haL, DD, B0H, B0L, DD, hbH, hbL, DD, DD);

  // output projection
  k_out16<<<dim3(512), blk, 0, stream>>>(hbH, hbL, Mout, bo, out);
}

// Round 5
// 783.808 us; speedup vs baseline: 3.3215x; 1.1137x over previous
//
#include <hip/hip_runtime.h>
#include <math.h>

#define DD 1024
#define MM 8192   // B*S rows
#define SS 128
#define DINN 64
#define DOUTN 64

typedef _Float16 f16;
typedef _Float16 f16x8 __attribute__((ext_vector_type(8)));
typedef _Float16 f16x4 __attribute__((ext_vector_type(4)));
typedef float    f32x4 __attribute__((ext_vector_type(4)));

// direct global->LDS, 16B per lane; LDS base must be wave-uniform
#define GLOAD_LDS(g, l) \
  __builtin_amdgcn_global_load_lds((const __attribute__((address_space(1))) void*)(g), \
                                   (__attribute__((address_space(3))) void*)(l), 16, 0, 0)

// split helpers: store hi' = f16(y)*64, lo' = f16((y - hi)*64); y = hi'/64 + lo'/4096.
__device__ __forceinline__ void split_store(float y, f16* __restrict__ hp, f16* __restrict__ lp, size_t idx) {
  f16 h = (f16)y;
  hp[idx] = h * (f16)64.0f;
  lp[idx] = (f16)((y - (float)h) * 64.0f);
}
__device__ __forceinline__ float join_load(const f16* __restrict__ hp, const f16* __restrict__ lp, size_t idx) {
  return (float)hp[idx] * 0.015625f + (float)lp[idx] * 0.000244140625f;
}

// ---------------------------------------------------------------------------
// Split-f16 MFMA GEMM.  Y = (Ahi+Alo/64)(Bhi+Blo/64)/4096, terms HH+HL+LH.
// A planes [M][K] (lda), B planes [N][K] (ldb), C planes [M][ldc].
// BM in {128,64}; BN=128; BK=32; 256 thr / 4 waves.
// LDS per-plane tiles [rows][32] f16, 16B-chunk XOR swizzle kc^=(row&3).
// SHIFT: store col = (n + SHIFT*(m>>6)) & 1023 (scalar path only).
// EPI:  y = y_old + tanh(acc/4096).
// SHIFT==0 uses a vectorized epilogue: per-wave LDS transpose staging (reuse
// sB, f16-typed so RAW ordering is compiler-visible) -> f16x8 global I/O.
// ---------------------------------------------------------------------------
template<int BM, bool EPI, int SHIFT>
__global__ __launch_bounds__(256)
void k_gemm16(const f16* __restrict__ Ahi, const f16* __restrict__ Alo, int lda,
              const f16* __restrict__ Bhi, const f16* __restrict__ Blo, int ldb,
              f16* __restrict__ Chi, f16* __restrict__ Clo, int ldc, int K) {
  constexpr int MT = BM / 32;      // 16x16 m-tiles per wave
  constexpr int AI = BM / 64;      // A staging iterations
  __shared__ f16 sA[2][2][BM * 32];
  __shared__ f16 sB[2][2][128 * 32];

  // XCD-aware swizzle (nwg % 8 == 0 for all our grids)
  const int nwg = gridDim.x * gridDim.y;
  int wg = blockIdx.y * gridDim.x + blockIdx.x;
  wg = (wg & 7) * (nwg >> 3) + (wg >> 3);
  const int bx = wg % gridDim.x, by = wg / gridDim.x;

  const int col0 = bx * 128, row0 = by * BM;
  const int u = threadIdx.x, lane = u & 63, wv = u >> 6;
  const int mh = (wv >> 1) * (BM >> 1);
  const int nh = (wv & 1) * 64;

  unsigned aoff[AI], boff[2];
  unsigned dstA[AI], dstB[2];
#pragma unroll
  for (int i = 0; i < AI; ++i) {
    const int P = i * 256 + u;
    const int row = P >> 2, kc = (P & 3) ^ (row & 3);
    aoff[i] = (unsigned)(row0 + row) * lda + kc * 8;
    dstA[i] = (i * 256 + wv * 64) * 8;
  }
#pragma unroll
  for (int i = 0; i < 2; ++i) {
    const int P = i * 256 + u;
    const int row = P >> 2, kc = (P & 3) ^ (row & 3);
    boff[i] = (unsigned)(col0 + row) * ldb + kc * 8;
    dstB[i] = (i * 256 + wv * 64) * 8;
  }

  const int frag = (lane & 15) * 32 + (((lane >> 4) ^ (lane & 3)) * 8);

  f32x4 acc[MT][4];
#pragma unroll
  for (int i = 0; i < MT; ++i)
#pragma unroll
    for (int j = 0; j < 4; ++j) acc[i][j] = (f32x4){0.f, 0.f, 0.f, 0.f};

  auto stage = [&](int b, int k0) {
#pragma unroll
    for (int i = 0; i < AI; ++i) {
      GLOAD_LDS(Ahi + aoff[i] + k0, &sA[b][0][dstA[i]]);
      GLOAD_LDS(Alo + aoff[i] + k0, &sA[b][1][dstA[i]]);
    }
#pragma unroll
    for (int i = 0; i < 2; ++i) {
      GLOAD_LDS(Bhi + boff[i] + k0, &sB[b][0][dstB[i]]);
      GLOAD_LDS(Blo + boff[i] + k0, &sB[b][1][dstB[i]]);
    }
  };

  const int niter = K >> 5;
  stage(0, 0);
  __syncthreads();

  int buf = 0;
  for (int it = 0; it < niter; ++it) {
    if (it + 1 < niter) stage(buf ^ 1, (it + 1) << 5);
    f16x8 aH[MT], aL[MT], bH[4], bL[4];
#pragma unroll
    for (int mt = 0; mt < MT; ++mt) {
      aH[mt] = *(const f16x8*)&sA[buf][0][(mh + mt * 16) * 32 + frag];
      aL[mt] = *(const f16x8*)&sA[buf][1][(mh + mt * 16) * 32 + frag];
    }
#pragma unroll
    for (int nt = 0; nt < 4; ++nt) {
      bH[nt] = *(const f16x8*)&sB[buf][0][(nh + nt * 16) * 32 + frag];
      bL[nt] = *(const f16x8*)&sB[buf][1][(nh + nt * 16) * 32 + frag];
    }
#pragma unroll
    for (int mt = 0; mt < MT; ++mt)
#pragma unroll
      for (int nt = 0; nt < 4; ++nt) {
        acc[mt][nt] = __builtin_amdgcn_mfma_f32_16x16x32_f16(aH[mt], bH[nt], acc[mt][nt], 0, 0, 0);
        acc[mt][nt] = __builtin_amdgcn_mfma_f32_16x16x32_f16(aH[mt], bL[nt], acc[mt][nt], 0, 0, 0);
        acc[mt][nt] = __builtin_amdgcn_mfma_f32_16x16x32_f16(aL[mt], bH[nt], acc[mt][nt], 0, 0, 0);
      }
    __syncthreads();
    buf ^= 1;
  }

  if constexpr (SHIFT == 0) {
    // ---- vectorized epilogue: per-wave LDS transpose staging (reuse sB) ----
    // region per wave: 16 rows x 84 f16 x 2 planes (84-stride spreads banks)
    f16* eH = ((f16*)sB) + wv * (16 * 84 * 2);
    f16* eL = eH + 16 * 84;
    const int lrow4 = (lane >> 4) << 2;  // 0,4,8,12
    const int lcol = lane & 15;
#pragma unroll
    for (int mt = 0; mt < MT; ++mt) {
#pragma unroll
      for (int nt = 0; nt < 4; ++nt) {
        const f32x4 a = acc[mt][nt];
#pragma unroll
        for (int r = 0; r < 4; ++r) {
          const float y = a[r] * 0.000244140625f;
          const f16 h = (f16)y;
          const int o = (lrow4 + r) * 84 + nt * 16 + lcol;
          eH[o] = h * (f16)64.0f;
          eL[o] = (f16)((y - (float)h) * 64.0f);
        }
      }
      // same-wave RAW through LDS: same-type accesses, compiler inserts waits
#pragma unroll
      for (int j = 0; j < 2; ++j) {
        const int idx = j * 64 + lane;
        const int row = idx >> 3, ch = idx & 7;
        const f16x8 vh = *(const f16x8*)&eH[row * 84 + ch * 8];
        const f16x8 vl = *(const f16x8*)&eL[row * 84 + ch * 8];
        const int m = row0 + mh + mt * 16 + row;
        const size_t gi = (size_t)m * ldc + col0 + nh + ch * 8;
        if (EPI) {
          const f16x8 oh = *(const f16x8*)&Chi[gi];
          const f16x8 ol = *(const f16x8*)&Clo[gi];
          f16x8 rh, rl;
#pragma unroll
          for (int q = 0; q < 8; ++q) {
            const float yn = (float)vh[q] * 0.015625f + (float)vl[q] * 0.000244140625f;
            const float y  = (float)oh[q] * 0.015625f + (float)ol[q] * 0.000244140625f + tanhf(yn);
            const f16 h = (f16)y;
            rh[q] = h * (f16)64.0f;
            rl[q] = (f16)((y - (float)h) * 64.0f);
          }
          *(f16x8*)&Chi[gi] = rh;
          *(f16x8*)&Clo[gi] = rl;
        } else {
          *(f16x8*)&Chi[gi] = vh;
          *(f16x8*)&Clo[gi] = vl;
        }
      }
    }
  } else {
    // ---- scalar epilogue (rotor shift folded into col index) ----
#pragma unroll
    for (int mt = 0; mt < MT; ++mt)
#pragma unroll
      for (int nt = 0; nt < 4; ++nt) {
        const f32x4 a = acc[mt][nt];
        const int n_base = col0 + nh + nt * 16 + (lane & 15);
#pragma unroll
        for (int r = 0; r < 4; ++r) {
          const int m = row0 + mh + mt * 16 + ((lane >> 4) << 2) + r;
          int n = (n_base + SHIFT * (m >> 6) + 2048) & (DD - 1);
          const size_t idx = (size_t)m * ldc + n;
          float y = a[r] * 0.000244140625f;
          if (EPI) y = join_load(Chi, Clo, idx) + tanhf(y);
          split_store(y, Chi, Clo, idx);
        }
      }
  }
}

// ---------------------------------------------------------------------------
// output projection as MFMA GEMM: out[b][t][c] = (h @ MoT^T)[r][c] + bo[c]
// A = h planes [8192][1024]; B = MoT planes [64][1024]; BM=64, grid 128.
// ---------------------------------------------------------------------------
__global__ __launch_bounds__(256)
void k_out_mfma(const f16* __restrict__ Ahi, const f16* __restrict__ Alo,
                const f16* __restrict__ Bhi, const f16* __restrict__ Blo,
                const float* __restrict__ bo, float* __restrict__ out) {
  __shared__ f16 sA[2][2][64 * 32];
  __shared__ f16 sB[2][2][64 * 32];
  const int row0 = blockIdx.x * 64;
  const int u = threadIdx.x, lane = u & 63, wv = u >> 6;
  const int mh = (wv >> 1) * 32, nh = (wv & 1) * 32;

  const int srow = u >> 2, skc = (u & 3) ^ (srow & 3);
  const unsigned aoff = (unsigned)(row0 + srow) * DD + skc * 8;
  const unsigned boff = (unsigned)srow * DD + skc * 8;
  const unsigned dst = (unsigned)(wv * 64) * 8;

  const int frag = (lane & 15) * 32 + (((lane >> 4) ^ (lane & 3)) * 8);

  f32x4 acc[2][2];
#pragma unroll
  for (int i = 0; i < 2; ++i)
#pragma unroll
    for (int j = 0; j < 2; ++j) acc[i][j] = (f32x4){0.f, 0.f, 0.f, 0.f};

  auto stage = [&](int b, int k0) {
    GLOAD_LDS(Ahi + aoff + k0, &sA[b][0][dst]);
    GLOAD_LDS(Alo + aoff + k0, &sA[b][1][dst]);
    GLOAD_LDS(Bhi + boff + k0, &sB[b][0][dst]);
    GLOAD_LDS(Blo + boff + k0, &sB[b][1][dst]);
  };

  stage(0, 0);
  __syncthreads();
  int buf = 0;
  for (int it = 0; it < 32; ++it) {
    if (it + 1 < 32) stage(buf ^ 1, (it + 1) << 5);
    f16x8 aH[2], aL[2], bH[2], bL[2];
#pragma unroll
    for (int mt = 0; mt < 2; ++mt) {
      aH[mt] = *(const f16x8*)&sA[buf][0][(mh + mt * 16) * 32 + frag];
      aL[mt] = *(const f16x8*)&sA[buf][1][(mh + mt * 16) * 32 + frag];
    }
#pragma unroll
    for (int nt = 0; nt < 2; ++nt) {
      bH[nt] = *(const f16x8*)&sB[buf][0][(nh + nt * 16) * 32 + frag];
      bL[nt] = *(const f16x8*)&sB[buf][1][(nh + nt * 16) * 32 + frag];
    }
#pragma unroll
    for (int mt = 0; mt < 2; ++mt)
#pragma unroll
      for (int nt = 0; nt < 2; ++nt) {
        acc[mt][nt] = __builtin_amdgcn_mfma_f32_16x16x32_f16(aH[mt], bH[nt], acc[mt][nt], 0, 0, 0);
        acc[mt][nt] = __builtin_amdgcn_mfma_f32_16x16x32_f16(aH[mt], bL[nt], acc[mt][nt], 0, 0, 0);
        acc[mt][nt] = __builtin_amdgcn_mfma_f32_16x16x32_f16(aL[mt], bH[nt], acc[mt][nt], 0, 0, 0);
      }
    __syncthreads();
    buf ^= 1;
  }

#pragma unroll
  for (int mt = 0; mt < 2; ++mt)
#pragma unroll
    for (int nt = 0; nt < 2; ++nt) {
      const f32x4 a = acc[mt][nt];
      const int c = nh + nt * 16 + (lane & 15);
      const float bias = bo[c];
#pragma unroll
      for (int r = 0; r < 4; ++r) {
        const int m = row0 + mh + mt * 16 + ((lane >> 4) << 2) + r;
        const int t = m >> 6, b = m & 63;
        out[((size_t)b * SS + t) * DOUTN + c] = a[r] * 0.000244140625f + bias;
      }
    }
}

// ---------------------------------------------------------------------------
// input projection: y[r][c] = sum_k A2[c][k]*x[b][t][k] + cvec[c], r = t*64+b,
// split-stored pre-rolled for rotor0: h[r][(c - t) & 1023].
// ---------------------------------------------------------------------------
__global__ __launch_bounds__(256)
void k_in16(const float* __restrict__ x, const float* __restrict__ A2,
            const float* __restrict__ cvec, f16* __restrict__ hH, f16* __restrict__ hL) {
  const int r0 = blockIdx.x * 64;
  const int c0 = blockIdx.y * 64;
  const int t = r0 >> 6;
  __shared__ float xs[64][65];
  __shared__ float a2s[64][68];
  const int u = threadIdx.x;
#pragma unroll
  for (int i = 0; i < 4; ++i) {
    const int idx = i * 256 + u;
    const int rr = idx >> 4, kc = (idx & 15) * 4;
    const float4 v = *(const float4*)&x[(size_t)rr * (SS * DINN) + t * DINN + kc];
    xs[rr][kc] = v.x; xs[rr][kc + 1] = v.y; xs[rr][kc + 2] = v.z; xs[rr][kc + 3] = v.w;
    *(float4*)&a2s[rr][kc] = *(const float4*)&A2[(size_t)(c0 + rr) * DINN + kc];
  }
  __syncthreads();
  const int rr = u & 63;
  const int cg = (u >> 6) * 16;
  float acc[16];
#pragma unroll
  for (int cc = 0; cc < 16; ++cc) acc[cc] = 0.f;
  for (int k = 0; k < DINN; ++k) {
    const float xv = xs[rr][k];
#pragma unroll
    for (int cc = 0; cc < 16; ++cc) acc[cc] += xv * a2s[cg + cc][k];
  }
  const int r = r0 + rr;
#pragma unroll
  for (int cc = 0; cc < 16; ++cc) {
    const int c = c0 + cg + cc;
    const int cr = (c - t + DD) & (DD - 1);
    split_store(acc[cc] + cvec[c], hH, hL, (size_t)r * DD + cr);
  }
}

// ---------------------------------------------------------------------------
// precompute: splits / transposes
// ---------------------------------------------------------------------------
__global__ __launch_bounds__(256)
void k_split(const float* __restrict__ src, f16* __restrict__ hi, f16* __restrict__ lo) {
  const int i = blockIdx.x * 256 + threadIdx.x;
  const float4 v = ((const float4*)src)[i];
  f16x4 h4, l4;
  const float vv[4] = {v.x, v.y, v.z, v.w};
#pragma unroll
  for (int j = 0; j < 4; ++j) {
    f16 h = (f16)vv[j];
    h4[j] = h * (f16)64.0f;
    l4[j] = (f16)((vv[j] - (float)h) * 64.0f);
  }
  ((f16x4*)hi)[i] = h4;
  ((f16x4*)lo)[i] = l4;
}

// transpose + split: src fp32 [dim][dim] (z-batched) -> planes = src^T
__global__ __launch_bounds__(256)
void k_splitT(const float* __restrict__ src, f16* __restrict__ hi, f16* __restrict__ lo, int dim) {
  const size_t zo = (size_t)blockIdx.z * dim * dim;
  src += zo; hi += zo; lo += zo;
  const int i0 = blockIdx.y * 64, j0 = blockIdx.x * 64;
  __shared__ float tb[64][68];
  const int u = threadIdx.x;
#pragma unroll
  for (int it = 0; it < 4; ++it) {
    const int idx = it * 256 + u, rr = idx >> 4, cc = (idx & 15) * 4;
    *(float4*)&tb[rr][cc] = *(const float4*)&src[(size_t)(i0 + rr) * dim + j0 + cc];
  }
  __syncthreads();
#pragma unroll
  for (int it = 0; it < 4; ++it) {
    const int idx = it * 256 + u, rr = idx >> 4, cc = (idx & 15) * 4;
    f16x4 h4, l4;
#pragma unroll
    for (int j = 0; j < 4; ++j) {
      const float y = tb[cc + j][rr];
      f16 h = (f16)y;
      h4[j] = h * (f16)64.0f;
      l4[j] = (f16)((y - (float)h) * 64.0f);
    }
    const size_t o = (size_t)(j0 + rr) * dim + i0 + cc;
    *(f16x4*)&hi[o] = h4;
    *(f16x4*)&lo[o] = l4;
  }
}

// S = R + R^T, split-stored (symmetric => [n][k] fine)
__global__ __launch_bounds__(256)
void k_symm_split(const float* __restrict__ R, f16* __restrict__ hi, f16* __restrict__ lo) {
  const int i0 = blockIdx.y * 64, j0 = blockIdx.x * 64;
  __shared__ float tb[64][68];
  const int u = threadIdx.x;
#pragma unroll
  for (int it = 0; it < 4; ++it) {
    const int idx = it * 256 + u, rr = idx >> 4, cc = (idx & 15) * 4;
    *(float4*)&tb[rr][cc] = *(const float4*)&R[(size_t)(j0 + rr) * DD + i0 + cc];
  }
  __syncthreads();
#pragma unroll
  for (int it = 0; it < 4; ++it) {
    const int idx = it * 256 + u, rr = idx >> 4, cc = (idx & 15) * 4;
    const float4 v = *(const float4*)&R[(size_t)(i0 + rr) * DD + j0 + cc];
    const float vv[4] = {v.x + tb[cc + 0][rr], v.y + tb[cc + 1][rr],
                         v.z + tb[cc + 2][rr], v.w + tb[cc + 3][rr]};
    f16x4 h4, l4;
#pragma unroll
    for (int j = 0; j < 4; ++j) {
      f16 h = (f16)vv[j];
      h4[j] = h * (f16)64.0f;
      l4[j] = (f16)((vv[j] - (float)h) * 64.0f);
    }
    const size_t o = (size_t)(i0 + rr) * DD + j0 + cc;
    *(f16x4*)&hi[o] = h4;
    *(f16x4*)&lo[o] = l4;
  }
}

// f16 plane transpose
__global__ __launch_bounds__(256)
void k_tr16(const f16* __restrict__ in, f16* __restrict__ o, int dim) {
  const int i0 = blockIdx.y * 64, j0 = blockIdx.x * 64;
  __shared__ f16 tb[64][72];
  const int u = threadIdx.x;
#pragma unroll
  for (int it = 0; it < 2; ++it) {
    const int C = it * 256 + u, row = C >> 3, ch = C & 7;
    *(f16x8*)&tb[row][ch * 8] = *(const f16x8*)&in[(size_t)(i0 + row) * dim + j0 + ch * 8];
  }
  __syncthreads();
#pragma unroll
  for (int it = 0; it < 2; ++it) {
    const int C = it * 256 + u, row = C >> 3, ch = C & 7;
    f16x8 v;
#pragma unroll
    for (int j = 0; j < 8; ++j) v[j] = tb[ch * 8 + j][row];
    *(f16x8*)&o[(size_t)(j0 + row) * dim + i0 + ch * 8] = v;
  }
}

// A2 = P @ Wi  ([1024][64])
__global__ __launch_bounds__(256)
void k_pwi(const float* __restrict__ P, const float* __restrict__ Wi,
           float* __restrict__ A2) {
  const int m0 = blockIdx.x * 4;
  __shared__ float Ps[4][1024];
  const int u = threadIdx.x;
#pragma unroll
  for (int i = 0; i < 4; ++i) {
    const int idx = i * 256 + u, mi = idx >> 8, kc = (idx & 255) * 4;
    *(float4*)&Ps[mi][kc] = *(const float4*)&P[(size_t)(m0 + mi) * DD + kc];
  }
  __syncthreads();
  const int n = u & 63, mi = u >> 6;
  float acc = 0.f;
  for (int k = 0; k < DD; ++k) acc += Ps[mi][k] * Wi[(size_t)k * DINN + n];
  A2[(size_t)(m0 + mi) * DINN + n] = acc;
}

// MoT planes [c][d] = sum_k P[d][k] * Wo[c][k]   (split-stored transposed)
__global__ __launch_bounds__(256)
void k_pwo(const float* __restrict__ P, const float* __restrict__ Wo_,
           f16* __restrict__ MoTH, f16* __restrict__ MoTL) {
  const int d0 = blockIdx.x * 4;
  __shared__ float Ps[4][1024];
  __shared__ float ws[64][65];
  const int u = threadIdx.x;
#pragma unroll
  for (int i = 0; i < 4; ++i) {
    const int idx = i * 256 + u, mi = idx >> 8, kc = (idx & 255) * 4;
    *(float4*)&Ps[mi][kc] = *(const float4*)&P[(size_t)(d0 + mi) * DD + kc];
  }
  const int c = u & 63, di = u >> 6;
  float acc = 0.f;
  for (int k0 = 0; k0 < DD; k0 += 64) {
    __syncthreads();
#pragma unroll
    for (int i = 0; i < 4; ++i) {
      const int idx = i * 256 + u, cc = idx >> 4, kc = (idx & 15) * 4;
      const float4 v = *(const float4*)&Wo_[(size_t)cc * DD + k0 + kc];
      ws[cc][kc] = v.x; ws[cc][kc + 1] = v.y; ws[cc][kc + 2] = v.z; ws[cc][kc + 3] = v.w;
    }
    __syncthreads();
    for (int kk = 0; kk < 64; ++kk) acc += Ps[di][k0 + kk] * ws[c][kk];
  }
  split_store(acc, MoTH, MoTL, (size_t)c * DD + d0 + di);
}

// cvec = P @ bi ; wave per row
__global__ __launch_bounds__(256)
void k_matvec(const float* __restrict__ P, const float* __restrict__ b,
              float* __restrict__ c) {
  const int row = blockIdx.x * 4 + (threadIdx.x >> 6);
  const int l = threadIdx.x & 63;
  float s = 0.f;
  for (int k = l; k < DD; k += 64) s += P[(size_t)row * DD + k] * b[k];
  for (int o = 32; o; o >>= 1) s += __shfl_down(s, o, 64);
  if (l == 0) c[row] = s;
}

// ---------------------------------------------------------------------------
extern "C" void kernel_launch(void* const* d_in, const int* in_sizes, int n_in,
                              void* d_out, int out_size, void* d_ws, size_t ws_size,
                              hipStream_t stream) {
  (void)in_sizes; (void)n_in; (void)out_size; (void)ws_size;
  const float* x    = (const float*)d_in[0];
  const float* Wi   = (const float*)d_in[1];
  const float* bi   = (const float*)d_in[2];
  const float* P    = (const float*)d_in[3];
  const float* rotW = (const float*)d_in[4];
  const float* F    = (const float*)d_in[5];
  const float* G    = (const float*)d_in[6];
  const float* R    = (const float*)d_in[7];
  const float* Wo   = (const float*)d_in[8];
  const float* bo   = (const float*)d_in[9];
  float* out = (float*)d_out;
  char* w = (char*)d_ws;

  constexpr size_t MB = 1u << 20;
  // h planes (f16, [8192][1024], hi scaled x64, lo = resid x64)
  f16* haH = (f16*)(w + 0 * MB);
  f16* haL = (f16*)(w + 16 * MB);
  f16* hbH = (f16*)(w + 32 * MB);
  f16* hbL = (f16*)(w + 48 * MB);
  // weight planes ([n][k] layout)
  f16* B0tH = (f16*)(w + 64 * MB); f16* B0tL = (f16*)(w + 66 * MB);   // W0^T
  f16* B12tH= (f16*)(w + 68 * MB); f16* B12tL= (f16*)(w + 70 * MB);   // W12^T
  f16* BssH = (f16*)(w + 72 * MB); f16* BssL = (f16*)(w + 74 * MB);   // R+R^T
  f16* B12H = (f16*)(w + 76 * MB); f16* B12L = (f16*)(w + 78 * MB);   // W12
  f16* B0H  = (f16*)(w + 80 * MB); f16* B0L  = (f16*)(w + 82 * MB);   // W0
  f16* BFH  = (f16*)(w + 84 * MB); f16* BFL  = (f16*)(w + 85 * MB + 512 * 1024); // F^T x3
  f16* BGH  = (f16*)(w + 87 * MB); f16* BGL  = (f16*)(w + 88 * MB + 512 * 1024); // G^T x3
  // fp32/plane small
  float* A2   = (float*)(w + 90 * MB);
  f16* MoTH   = (f16*)(w + 90 * MB + 256 * 1024);
  f16* MoTL   = (f16*)(w + 90 * MB + 384 * 1024);
  float* cvec = (float*)(w + 90 * MB + 512 * 1024);
  // temp W1/W2 split planes alias hb region (dead until first GEMM writes hb)
  f16* W1sH = (f16*)(w + 32 * MB); f16* W1sL = (f16*)(w + 34 * MB);
  f16* W2tH = (f16*)(w + 36 * MB); f16* W2tL = (f16*)(w + 38 * MB);

  const float* W0 = rotW;
  const float* W1 = rotW + (1u << 20);
  const float* W2 = rotW + (2u << 20);

  const dim3 blk(256);
  const size_t FGQ = (size_t)512 * 512;

  // ---- precompute: weight splits ----
  k_split     <<<dim3(1024), blk, 0, stream>>>(W1, W1sH, W1sL);                 // W1 [m][k]
  k_splitT    <<<dim3(16, 16), blk, 0, stream>>>(W2, W2tH, W2tL, DD);           // W2^T [n][k]
  // W12 = W1 @ W2 in split-f16 (BM=64 -> 128 blocks for occupancy)
  k_gemm16<64, false, 0><<<dim3(8, 16), blk, 0, stream>>>(W1sH, W1sL, DD, W2tH, W2tL, DD, B12H, B12L, DD, DD);
  k_tr16      <<<dim3(16, 16), blk, 0, stream>>>(B12H, B12tH, DD);              // W12^T planes
  k_tr16      <<<dim3(16, 16), blk, 0, stream>>>(B12L, B12tL, DD);
  k_symm_split<<<dim3(16, 16), blk, 0, stream>>>(R, BssH, BssL);
  k_splitT    <<<dim3(16, 16), blk, 0, stream>>>(W0, B0tH, B0tL, DD);           // W0^T
  k_split     <<<dim3(1024), blk, 0, stream>>>(W0, B0H, B0L);                   // W0 as-is
  k_splitT    <<<dim3(8, 8, 3), blk, 0, stream>>>(F, BFH, BFL, 512);            // F_i^T
  k_splitT    <<<dim3(8, 8, 3), blk, 0, stream>>>(G, BGH, BGL, 512);            // G_i^T
  k_pwi       <<<dim3(256), blk, 0, stream>>>(P, Wi, A2);
  k_pwo       <<<dim3(256), blk, 0, stream>>>(P, Wo, MoTH, MoTL);
  k_matvec    <<<dim3(256), blk, 0, stream>>>(P, bi, cvec);

  // ---- main pipeline ----
  k_in16<<<dim3(128, 16), blk, 0, stream>>>(x, A2, cvec, haH, haL);             // pre-rolled (-t)

  // rotor 0 fwd (A pre-rolled, store +t)
  k_gemm16<128, false, +1><<<dim3(8, 64), blk, 0, stream>>>(haH, haL, DD, B0tH, B0tL, DD, hbH, hbL, DD, DD);
  // rotors 1,2 precomposed
  k_gemm16<128, false, 0><<<dim3(8, 64), blk, 0, stream>>>(hbH, hbL, DD, B12tH, B12tL, DD, haH, haL, DD, DD);
  // reversible blocks fwd (in place on ha; h2 = cols 512.., y1 = cols 0..)
  for (int i = 0; i < 3; ++i) {
    k_gemm16<64, true, 0><<<dim3(4, 128), blk, 0, stream>>>(haH + 512, haL + 512, DD, BFH + i * FGQ, BFL + i * FGQ, 512, haH, haL, DD, 512);
    k_gemm16<64, true, 0><<<dim3(4, 128), blk, 0, stream>>>(haH, haL, DD, BGH + i * FGQ, BGL + i * FGQ, 512, haH + 512, haL + 512, DD, 512);
  }
  // reflector
  k_gemm16<128, false, 0><<<dim3(8, 64), blk, 0, stream>>>(haH, haL, DD, BssH, BssL, DD, hbH, hbL, DD, DD);
  // reversible blocks reversed (in place on hb)
  for (int i = 2; i >= 0; --i) {
    k_gemm16<64, true, 0><<<dim3(4, 128), blk, 0, stream>>>(hbH + 512, hbL + 512, DD, BFH + i * FGQ, BFL + i * FGQ, 512, hbH, hbL, DD, 512);
    k_gemm16<64, true, 0><<<dim3(4, 128), blk, 0, stream>>>(hbH, hbL, DD, BGH + i * FGQ, BGL + i * FGQ, 512, hbH + 512, hbL + 512, DD, 512);
  }
  // rotors inverse: W12^T-mult (B = W12 as-is), store pre-rolled (-t)
  k_gemm16<128, false, -1><<<dim3(8, 64), blk, 0, stream>>>(hbH, hbL, DD, B12H, B12L, DD, haH, haL, DD, DD);
  // rotor 0 inverse: W0^T-mult (B = W0 as-is), store +t -> linear
  k_gemm16<128, false, +1><<<dim3(8, 64), blk, 0, stream>>>(haH, haL, DD, B0H, B0L, DD, hbH, hbL, DD, DD);

  // output projection (MFMA on already-split h planes)
  k_out_mfma<<<dim3(128), blk, 0, stream>>>(hbH, hbL, MoTH, MoTL, bo, out);
}

// Round 6
// 753.031 us; speedup vs baseline: 3.4572x; 1.0409x over previous
//
#include <hip/hip_runtime.h>
#include <math.h>

#define DD 1024
#define MM 8192   // B*S rows
#define SS 128
#define DINN 64
#define DOUTN 64

typedef _Float16 f16;
typedef _Float16 f16x8 __attribute__((ext_vector_type(8)));
typedef _Float16 f16x4 __attribute__((ext_vector_type(4)));
typedef float    f32x4 __attribute__((ext_vector_type(4)));

// direct global->LDS, 16B per lane; LDS base must be wave-uniform
#define GLOAD_LDS(g, l) \
  __builtin_amdgcn_global_load_lds((const __attribute__((address_space(1))) void*)(g), \
                                   (__attribute__((address_space(3))) void*)(l), 16, 0, 0)

// split helpers: store hi' = f16(y)*64, lo' = f16((y - hi)*64); y = hi'/64 + lo'/4096.
__device__ __forceinline__ void split_store(float y, f16* __restrict__ hp, f16* __restrict__ lp, size_t idx) {
  f16 h = (f16)y;
  hp[idx] = h * (f16)64.0f;
  lp[idx] = (f16)((y - (float)h) * 64.0f);
}
__device__ __forceinline__ float join_load(const f16* __restrict__ hp, const f16* __restrict__ lp, size_t idx) {
  return (float)hp[idx] * 0.015625f + (float)lp[idx] * 0.000244140625f;
}

// ---------------------------------------------------------------------------
// Split-f16 MFMA GEMM.  Y = (Ahi+Alo/64)(Bhi+Blo/64)/4096, terms HH+HL+LH.
// A planes [M][K] (lda), B planes [N][K] (ldb), C planes [M][ldc].
// BM in {128,64}; BN=128; BK=32; 256 thr / 4 waves.
// LDS per-plane tiles [rows][32] f16, 16B-chunk XOR swizzle kc^=(row&3).
// SHIFT: store col = (n + SHIFT*(m>>6)) & 1023 (scalar path only).
// EPI:  y = y_old + tanh(acc/4096).
// SHIFT==0 uses a vectorized epilogue: per-wave LDS transpose staging (reuse
// sB, f16-typed so RAW ordering is compiler-visible) -> f16x8 global I/O.
// ---------------------------------------------------------------------------
template<int BM, bool EPI, int SHIFT>
__global__ __launch_bounds__(256)
void k_gemm16(const f16* __restrict__ Ahi, const f16* __restrict__ Alo, int lda,
              const f16* __restrict__ Bhi, const f16* __restrict__ Blo, int ldb,
              f16* __restrict__ Chi, f16* __restrict__ Clo, int ldc, int K) {
  constexpr int MT = BM / 32;      // 16x16 m-tiles per wave
  constexpr int AI = BM / 64;      // A staging iterations
  __shared__ f16 sA[2][2][BM * 32];
  __shared__ f16 sB[2][2][128 * 32];

  // XCD-aware swizzle (nwg % 8 == 0 for all our grids)
  const int nwg = gridDim.x * gridDim.y;
  int wg = blockIdx.y * gridDim.x + blockIdx.x;
  wg = (wg & 7) * (nwg >> 3) + (wg >> 3);
  const int bx = wg % gridDim.x, by = wg / gridDim.x;

  const int col0 = bx * 128, row0 = by * BM;
  const int u = threadIdx.x, lane = u & 63, wv = u >> 6;
  const int mh = (wv >> 1) * (BM >> 1);
  const int nh = (wv & 1) * 64;

  unsigned aoff[AI], boff[2];
  unsigned dstA[AI], dstB[2];
#pragma unroll
  for (int i = 0; i < AI; ++i) {
    const int P = i * 256 + u;
    const int row = P >> 2, kc = (P & 3) ^ (row & 3);
    aoff[i] = (unsigned)(row0 + row) * lda + kc * 8;
    dstA[i] = (i * 256 + wv * 64) * 8;
  }
#pragma unroll
  for (int i = 0; i < 2; ++i) {
    const int P = i * 256 + u;
    const int row = P >> 2, kc = (P & 3) ^ (row & 3);
    boff[i] = (unsigned)(col0 + row) * ldb + kc * 8;
    dstB[i] = (i * 256 + wv * 64) * 8;
  }

  const int frag = (lane & 15) * 32 + (((lane >> 4) ^ (lane & 3)) * 8);

  f32x4 acc[MT][4];
#pragma unroll
  for (int i = 0; i < MT; ++i)
#pragma unroll
    for (int j = 0; j < 4; ++j) acc[i][j] = (f32x4){0.f, 0.f, 0.f, 0.f};

  auto stage = [&](int b, int k0) {
#pragma unroll
    for (int i = 0; i < AI; ++i) {
      GLOAD_LDS(Ahi + aoff[i] + k0, &sA[b][0][dstA[i]]);
      GLOAD_LDS(Alo + aoff[i] + k0, &sA[b][1][dstA[i]]);
    }
#pragma unroll
    for (int i = 0; i < 2; ++i) {
      GLOAD_LDS(Bhi + boff[i] + k0, &sB[b][0][dstB[i]]);
      GLOAD_LDS(Blo + boff[i] + k0, &sB[b][1][dstB[i]]);
    }
  };

  const int niter = K >> 5;
  stage(0, 0);
  __syncthreads();

  int buf = 0;
  for (int it = 0; it < niter; ++it) {
    if (it + 1 < niter) stage(buf ^ 1, (it + 1) << 5);
    f16x8 aH[MT], aL[MT], bH[4], bL[4];
#pragma unroll
    for (int mt = 0; mt < MT; ++mt) {
      aH[mt] = *(const f16x8*)&sA[buf][0][(mh + mt * 16) * 32 + frag];
      aL[mt] = *(const f16x8*)&sA[buf][1][(mh + mt * 16) * 32 + frag];
    }
#pragma unroll
    for (int nt = 0; nt < 4; ++nt) {
      bH[nt] = *(const f16x8*)&sB[buf][0][(nh + nt * 16) * 32 + frag];
      bL[nt] = *(const f16x8*)&sB[buf][1][(nh + nt * 16) * 32 + frag];
    }
#pragma unroll
    for (int mt = 0; mt < MT; ++mt)
#pragma unroll
      for (int nt = 0; nt < 4; ++nt) {
        acc[mt][nt] = __builtin_amdgcn_mfma_f32_16x16x32_f16(aH[mt], bH[nt], acc[mt][nt], 0, 0, 0);
        acc[mt][nt] = __builtin_amdgcn_mfma_f32_16x16x32_f16(aH[mt], bL[nt], acc[mt][nt], 0, 0, 0);
        acc[mt][nt] = __builtin_amdgcn_mfma_f32_16x16x32_f16(aL[mt], bH[nt], acc[mt][nt], 0, 0, 0);
      }
    __syncthreads();
    buf ^= 1;
  }

  if constexpr (SHIFT == 0) {
    // ---- vectorized epilogue: per-wave LDS transpose staging (reuse sB) ----
    f16* eH = ((f16*)sB) + wv * (16 * 84 * 2);
    f16* eL = eH + 16 * 84;
    const int lrow4 = (lane >> 4) << 2;
    const int lcol = lane & 15;
#pragma unroll
    for (int mt = 0; mt < MT; ++mt) {
#pragma unroll
      for (int nt = 0; nt < 4; ++nt) {
        const f32x4 a = acc[mt][nt];
#pragma unroll
        for (int r = 0; r < 4; ++r) {
          const float y = a[r] * 0.000244140625f;
          const f16 h = (f16)y;
          const int o = (lrow4 + r) * 84 + nt * 16 + lcol;
          eH[o] = h * (f16)64.0f;
          eL[o] = (f16)((y - (float)h) * 64.0f);
        }
      }
#pragma unroll
      for (int j = 0; j < 2; ++j) {
        const int idx = j * 64 + lane;
        const int row = idx >> 3, ch = idx & 7;
        const f16x8 vh = *(const f16x8*)&eH[row * 84 + ch * 8];
        const f16x8 vl = *(const f16x8*)&eL[row * 84 + ch * 8];
        const int m = row0 + mh + mt * 16 + row;
        const size_t gi = (size_t)m * ldc + col0 + nh + ch * 8;
        if (EPI) {
          const f16x8 oh = *(const f16x8*)&Chi[gi];
          const f16x8 ol = *(const f16x8*)&Clo[gi];
          f16x8 rh, rl;
#pragma unroll
          for (int q = 0; q < 8; ++q) {
            const float yn = (float)vh[q] * 0.015625f + (float)vl[q] * 0.000244140625f;
            const float y  = (float)oh[q] * 0.015625f + (float)ol[q] * 0.000244140625f + tanhf(yn);
            const f16 h = (f16)y;
            rh[q] = h * (f16)64.0f;
            rl[q] = (f16)((y - (float)h) * 64.0f);
          }
          *(f16x8*)&Chi[gi] = rh;
          *(f16x8*)&Clo[gi] = rl;
        } else {
          *(f16x8*)&Chi[gi] = vh;
          *(f16x8*)&Clo[gi] = vl;
        }
      }
    }
  } else {
    // ---- scalar epilogue (rotor shift folded into col index) ----
#pragma unroll
    for (int mt = 0; mt < MT; ++mt)
#pragma unroll
      for (int nt = 0; nt < 4; ++nt) {
        const f32x4 a = acc[mt][nt];
        const int n_base = col0 + nh + nt * 16 + (lane & 15);
#pragma unroll
        for (int r = 0; r < 4; ++r) {
          const int m = row0 + mh + mt * 16 + ((lane >> 4) << 2) + r;
          int n = (n_base + SHIFT * (m >> 6) + 2048) & (DD - 1);
          const size_t idx = (size_t)m * ldc + n;
          float y = a[r] * 0.000244140625f;
          if (EPI) y = join_load(Chi, Clo, idx) + tanhf(y);
          split_store(y, Chi, Clo, idx);
        }
      }
  }
}

// ---------------------------------------------------------------------------
// output projection as MFMA GEMM: out[b][t][c] = (h @ MoT^T)[r][c] + bo[c]
// A = h planes [8192][1024]; B = MoT planes [64][1024]; BM=64, grid 128.
// ---------------------------------------------------------------------------
__global__ __launch_bounds__(256)
void k_out_mfma(const f16* __restrict__ Ahi, const f16* __restrict__ Alo,
                const f16* __restrict__ Bhi, const f16* __restrict__ Blo,
                const float* __restrict__ bo, float* __restrict__ out) {
  __shared__ f16 sA[2][2][64 * 32];
  __shared__ f16 sB[2][2][64 * 32];
  const int row0 = blockIdx.x * 64;
  const int u = threadIdx.x, lane = u & 63, wv = u >> 6;
  const int mh = (wv >> 1) * 32, nh = (wv & 1) * 32;

  const int srow = u >> 2, skc = (u & 3) ^ (srow & 3);
  const unsigned aoff = (unsigned)(row0 + srow) * DD + skc * 8;
  const unsigned boff = (unsigned)srow * DD + skc * 8;
  const unsigned dst = (unsigned)(wv * 64) * 8;

  const int frag = (lane & 15) * 32 + (((lane >> 4) ^ (lane & 3)) * 8);

  f32x4 acc[2][2];
#pragma unroll
  for (int i = 0; i < 2; ++i)
#pragma unroll
    for (int j = 0; j < 2; ++j) acc[i][j] = (f32x4){0.f, 0.f, 0.f, 0.f};

  auto stage = [&](int b, int k0) {
    GLOAD_LDS(Ahi + aoff + k0, &sA[b][0][dst]);
    GLOAD_LDS(Alo + aoff + k0, &sA[b][1][dst]);
    GLOAD_LDS(Bhi + boff + k0, &sB[b][0][dst]);
    GLOAD_LDS(Blo + boff + k0, &sB[b][1][dst]);
  };

  stage(0, 0);
  __syncthreads();
  int buf = 0;
  for (int it = 0; it < 32; ++it) {
    if (it + 1 < 32) stage(buf ^ 1, (it + 1) << 5);
    f16x8 aH[2], aL[2], bH[2], bL[2];
#pragma unroll
    for (int mt = 0; mt < 2; ++mt) {
      aH[mt] = *(const f16x8*)&sA[buf][0][(mh + mt * 16) * 32 + frag];
      aL[mt] = *(const f16x8*)&sA[buf][1][(mh + mt * 16) * 32 + frag];
    }
#pragma unroll
    for (int nt = 0; nt < 2; ++nt) {
      bH[nt] = *(const f16x8*)&sB[buf][0][(nh + nt * 16) * 32 + frag];
      bL[nt] = *(const f16x8*)&sB[buf][1][(nh + nt * 16) * 32 + frag];
    }
#pragma unroll
    for (int mt = 0; mt < 2; ++mt)
#pragma unroll
      for (int nt = 0; nt < 2; ++nt) {
        acc[mt][nt] = __builtin_amdgcn_mfma_f32_16x16x32_f16(aH[mt], bH[nt], acc[mt][nt], 0, 0, 0);
        acc[mt][nt] = __builtin_amdgcn_mfma_f32_16x16x32_f16(aH[mt], bL[nt], acc[mt][nt], 0, 0, 0);
        acc[mt][nt] = __builtin_amdgcn_mfma_f32_16x16x32_f16(aL[mt], bH[nt], acc[mt][nt], 0, 0, 0);
      }
    __syncthreads();
    buf ^= 1;
  }

#pragma unroll
  for (int mt = 0; mt < 2; ++mt)
#pragma unroll
    for (int nt = 0; nt < 2; ++nt) {
      const f32x4 a = acc[mt][nt];
      const int c = nh + nt * 16 + (lane & 15);
      const float bias = bo[c];
#pragma unroll
      for (int r = 0; r < 4; ++r) {
        const int m = row0 + mh + mt * 16 + ((lane >> 4) << 2) + r;
        const int t = m >> 6, b = m & 63;
        out[((size_t)b * SS + t) * DOUTN + c] = a[r] * 0.000244140625f + bias;
      }
    }
}

// ---------------------------------------------------------------------------
// input projection, read-side roll: block covers ROLLED cols j in [c0,c0+64):
//   h[r][j] = sum_k x[b][t][k] * A2[(j+t)&1023][k] + cvec[(j+t)&1023]
// Roll only offsets which A2 ROWS are staged (row-granular, coalesced);
// h-plane writes are linear, aligned f16x8.
// ---------------------------------------------------------------------------
__global__ __launch_bounds__(256)
void k_in16(const float* __restrict__ x, const float* __restrict__ A2,
            const float* __restrict__ cvec, f16* __restrict__ hH, f16* __restrict__ hL) {
  const int r0 = blockIdx.x * 64;         // 64 rows, t uniform per block
  const int c0 = blockIdx.y * 64;         // 64 rolled cols
  const int t = r0 >> 6;
  __shared__ float xs[64][65];
  __shared__ float a2s[64][67];
  __shared__ float cvs[64];
  const int u = threadIdx.x;
#pragma unroll
  for (int i = 0; i < 4; ++i) {
    const int idx = i * 256 + u;
    const int rr = idx >> 4, kc = (idx & 15) * 4;
    const float4 v = *(const float4*)&x[(size_t)rr * (SS * DINN) + t * DINN + kc];
    xs[rr][kc] = v.x; xs[rr][kc + 1] = v.y; xs[rr][kc + 2] = v.z; xs[rr][kc + 3] = v.w;
    const int src = (c0 + rr + t) & (DD - 1);
    const float4 a = *(const float4*)&A2[(size_t)src * DINN + kc];
    a2s[rr][kc] = a.x; a2s[rr][kc + 1] = a.y; a2s[rr][kc + 2] = a.z; a2s[rr][kc + 3] = a.w;
  }
  if (u < 64) cvs[u] = cvec[(c0 + u + t) & (DD - 1)];
  __syncthreads();
  const int rr = u >> 2;          // row 0..63 (4 lanes share a row)
  const int cg = (u & 3) * 16;    // col group
  float acc[16];
#pragma unroll
  for (int cc = 0; cc < 16; ++cc) acc[cc] = cvs[cg + cc];
  for (int k = 0; k < DINN; ++k) {
    const float xv = xs[rr][k];
#pragma unroll
    for (int cc = 0; cc < 16; ++cc) acc[cc] += xv * a2s[cg + cc][k];
  }
  const size_t base = (size_t)(r0 + rr) * DD + c0 + cg;
#pragma unroll
  for (int half = 0; half < 2; ++half) {
    f16x8 h8, l8;
#pragma unroll
    for (int q = 0; q < 8; ++q) {
      const float y = acc[half * 8 + q];
      const f16 h = (f16)y;
      h8[q] = h * (f16)64.0f;
      l8[q] = (f16)((y - (float)h) * 64.0f);
    }
    *(f16x8*)&hH[base + half * 8] = h8;
    *(f16x8*)&hL[base + half * 8] = l8;
  }
}

// ---------------------------------------------------------------------------
// precompute: splits / transposes
// ---------------------------------------------------------------------------
__global__ __launch_bounds__(256)
void k_split(const float* __restrict__ src, f16* __restrict__ hi, f16* __restrict__ lo) {
  const int i = blockIdx.x * 256 + threadIdx.x;
  const float4 v = ((const float4*)src)[i];
  f16x4 h4, l4;
  const float vv[4] = {v.x, v.y, v.z, v.w};
#pragma unroll
  for (int j = 0; j < 4; ++j) {
    f16 h = (f16)vv[j];
    h4[j] = h * (f16)64.0f;
    l4[j] = (f16)((vv[j] - (float)h) * 64.0f);
  }
  ((f16x4*)hi)[i] = h4;
  ((f16x4*)lo)[i] = l4;
}

// transpose + split: src fp32 [dim][dim] (z-batched) -> planes = src^T
__global__ __launch_bounds__(256)
void k_splitT(const float* __restrict__ src, f16* __restrict__ hi, f16* __restrict__ lo, int dim) {
  const size_t zo = (size_t)blockIdx.z * dim * dim;
  src += zo; hi += zo; lo += zo;
  const int i0 = blockIdx.y * 64, j0 = blockIdx.x * 64;
  __shared__ float tb[64][68];
  const int u = threadIdx.x;
#pragma unroll
  for (int it = 0; it < 4; ++it) {
    const int idx = it * 256 + u, rr = idx >> 4, cc = (idx & 15) * 4;
    *(float4*)&tb[rr][cc] = *(const float4*)&src[(size_t)(i0 + rr) * dim + j0 + cc];
  }
  __syncthreads();
#pragma unroll
  for (int it = 0; it < 4; ++it) {
    const int idx = it * 256 + u, rr = idx >> 4, cc = (idx & 15) * 4;
    f16x4 h4, l4;
#pragma unroll
    for (int j = 0; j < 4; ++j) {
      const float y = tb[cc + j][rr];
      f16 h = (f16)y;
      h4[j] = h * (f16)64.0f;
      l4[j] = (f16)((y - (float)h) * 64.0f);
    }
    const size_t o = (size_t)(j0 + rr) * dim + i0 + cc;
    *(f16x4*)&hi[o] = h4;
    *(f16x4*)&lo[o] = l4;
  }
}

// S = R + R^T, split-stored (symmetric => [n][k] fine)
__global__ __launch_bounds__(256)
void k_symm_split(const float* __restrict__ R, f16* __restrict__ hi, f16* __restrict__ lo) {
  const int i0 = blockIdx.y * 64, j0 = blockIdx.x * 64;
  __shared__ float tb[64][68];
  const int u = threadIdx.x;
#pragma unroll
  for (int it = 0; it < 4; ++it) {
    const int idx = it * 256 + u, rr = idx >> 4, cc = (idx & 15) * 4;
    *(float4*)&tb[rr][cc] = *(const float4*)&R[(size_t)(j0 + rr) * DD + i0 + cc];
  }
  __syncthreads();
#pragma unroll
  for (int it = 0; it < 4; ++it) {
    const int idx = it * 256 + u, rr = idx >> 4, cc = (idx & 15) * 4;
    const float4 v = *(const float4*)&R[(size_t)(i0 + rr) * DD + j0 + cc];
    const float vv[4] = {v.x + tb[cc + 0][rr], v.y + tb[cc + 1][rr],
                         v.z + tb[cc + 2][rr], v.w + tb[cc + 3][rr]};
    f16x4 h4, l4;
#pragma unroll
    for (int j = 0; j < 4; ++j) {
      f16 h = (f16)vv[j];
      h4[j] = h * (f16)64.0f;
      l4[j] = (f16)((vv[j] - (float)h) * 64.0f);
    }
    const size_t o = (size_t)(i0 + rr) * DD + j0 + cc;
    *(f16x4*)&hi[o] = h4;
    *(f16x4*)&lo[o] = l4;
  }
}

// f16 plane transpose
__global__ __launch_bounds__(256)
void k_tr16(const f16* __restrict__ in, f16* __restrict__ o, int dim) {
  const int i0 = blockIdx.y * 64, j0 = blockIdx.x * 64;
  __shared__ f16 tb[64][72];
  const int u = threadIdx.x;
#pragma unroll
  for (int it = 0; it < 2; ++it) {
    const int C = it * 256 + u, row = C >> 3, ch = C & 7;
    *(f16x8*)&tb[row][ch * 8] = *(const f16x8*)&in[(size_t)(i0 + row) * dim + j0 + ch * 8];
  }
  __syncthreads();
#pragma unroll
  for (int it = 0; it < 2; ++it) {
    const int C = it * 256 + u, row = C >> 3, ch = C & 7;
    f16x8 v;
#pragma unroll
    for (int j = 0; j < 8; ++j) v[j] = tb[ch * 8 + j][row];
    *(f16x8*)&o[(size_t)(j0 + row) * dim + i0 + ch * 8] = v;
  }
}

// A2 = P @ Wi  ([1024][64])
__global__ __launch_bounds__(256)
void k_pwi(const float* __restrict__ P, const float* __restrict__ Wi,
           float* __restrict__ A2) {
  const int m0 = blockIdx.x * 4;
  __shared__ float Ps[4][1024];
  const int u = threadIdx.x;
#pragma unroll
  for (int i = 0; i < 4; ++i) {
    const int idx = i * 256 + u, mi = idx >> 8, kc = (idx & 255) * 4;
    *(float4*)&Ps[mi][kc] = *(const float4*)&P[(size_t)(m0 + mi) * DD + kc];
  }
  __syncthreads();
  const int n = u & 63, mi = u >> 6;
  float acc = 0.f;
  for (int k = 0; k < DD; ++k) acc += Ps[mi][k] * Wi[(size_t)k * DINN + n];
  A2[(size_t)(m0 + mi) * DINN + n] = acc;
}

// MoT planes [c][d] = sum_k P[d][k] * Wo[c][k]   (split-stored transposed)
__global__ __launch_bounds__(256)
void k_pwo(const float* __restrict__ P, const float* __restrict__ Wo_,
           f16* __restrict__ MoTH, f16* __restrict__ MoTL) {
  const int d0 = blockIdx.x * 4;
  __shared__ float Ps[4][1024];
  __shared__ float ws[64][65];
  const int u = threadIdx.x;
#pragma unroll
  for (int i = 0; i < 4; ++i) {
    const int idx = i * 256 + u, mi = idx >> 8, kc = (idx & 255) * 4;
    *(float4*)&Ps[mi][kc] = *(const float4*)&P[(size_t)(d0 + mi) * DD + kc];
  }
  const int c = u & 63, di = u >> 6;
  float acc = 0.f;
  for (int k0 = 0; k0 < DD; k0 += 64) {
    __syncthreads();
#pragma unroll
    for (int i = 0; i < 4; ++i) {
      const int idx = i * 256 + u, cc = idx >> 4, kc = (idx & 15) * 4;
      const float4 v = *(const float4*)&Wo_[(size_t)cc * DD + k0 + kc];
      ws[cc][kc] = v.x; ws[cc][kc + 1] = v.y; ws[cc][kc + 2] = v.z; ws[cc][kc + 3] = v.w;
    }
    __syncthreads();
    for (int kk = 0; kk < 64; ++kk) acc += Ps[di][k0 + kk] * ws[c][kk];
  }
  split_store(acc, MoTH, MoTL, (size_t)c * DD + d0 + di);
}

// cvec = P @ bi ; wave per row
__global__ __launch_bounds__(256)
void k_matvec(const float* __restrict__ P, const float* __restrict__ b,
              float* __restrict__ c) {
  const int row = blockIdx.x * 4 + (threadIdx.x >> 6);
  const int l = threadIdx.x & 63;
  float s = 0.f;
  for (int k = l; k < DD; k += 64) s += P[(size_t)row * DD + k] * b[k];
  for (int o = 32; o; o >>= 1) s += __shfl_down(s, o, 64);
  if (l == 0) c[row] = s;
}

// ---------------------------------------------------------------------------
extern "C" void kernel_launch(void* const* d_in, const int* in_sizes, int n_in,
                              void* d_out, int out_size, void* d_ws, size_t ws_size,
                              hipStream_t stream) {
  (void)in_sizes; (void)n_in; (void)out_size; (void)ws_size;
  const float* x    = (const float*)d_in[0];
  const float* Wi   = (const float*)d_in[1];
  const float* bi   = (const float*)d_in[2];
  const float* P    = (const float*)d_in[3];
  const float* rotW = (const float*)d_in[4];
  const float* F    = (const float*)d_in[5];
  const float* G    = (const float*)d_in[6];
  const float* R    = (const float*)d_in[7];
  const float* Wo   = (const float*)d_in[8];
  const float* bo   = (const float*)d_in[9];
  float* out = (float*)d_out;
  char* w = (char*)d_ws;

  constexpr size_t MB = 1u << 20;
  // h planes (f16, [8192][1024], hi scaled x64, lo = resid x64)
  f16* haH = (f16*)(w + 0 * MB);
  f16* haL = (f16*)(w + 16 * MB);
  f16* hbH = (f16*)(w + 32 * MB);
  f16* hbL = (f16*)(w + 48 * MB);
  // weight planes ([n][k] layout)
  f16* B0tH = (f16*)(w + 64 * MB); f16* B0tL = (f16*)(w + 66 * MB);   // W0^T
  f16* B12tH= (f16*)(w + 68 * MB); f16* B12tL= (f16*)(w + 70 * MB);   // W12^T
  f16* BssH = (f16*)(w + 72 * MB); f16* BssL = (f16*)(w + 74 * MB);   // R+R^T
  f16* B12H = (f16*)(w + 76 * MB); f16* B12L = (f16*)(w + 78 * MB);   // W12
  f16* B0H  = (f16*)(w + 80 * MB); f16* B0L  = (f16*)(w + 82 * MB);   // W0
  f16* BFH  = (f16*)(w + 84 * MB); f16* BFL  = (f16*)(w + 85 * MB + 512 * 1024); // F^T x3
  f16* BGH  = (f16*)(w + 87 * MB); f16* BGL  = (f16*)(w + 88 * MB + 512 * 1024); // G^T x3
  // fp32/plane small
  float* A2   = (float*)(w + 90 * MB);
  f16* MoTH   = (f16*)(w + 90 * MB + 256 * 1024);
  f16* MoTL   = (f16*)(w + 90 * MB + 384 * 1024);
  float* cvec = (float*)(w + 90 * MB + 512 * 1024);
  // temp W1/W2 split planes alias hb region (dead until first GEMM writes hb)
  f16* W1sH = (f16*)(w + 32 * MB); f16* W1sL = (f16*)(w + 34 * MB);
  f16* W2tH = (f16*)(w + 36 * MB); f16* W2tL = (f16*)(w + 38 * MB);

  const float* W0 = rotW;
  const float* W1 = rotW + (1u << 20);
  const float* W2 = rotW + (2u << 20);

  const dim3 blk(256);
  const size_t FGQ = (size_t)512 * 512;

  // ---- precompute: weight splits ----
  k_split     <<<dim3(1024), blk, 0, stream>>>(W1, W1sH, W1sL);                 // W1 [m][k]
  k_splitT    <<<dim3(16, 16), blk, 0, stream>>>(W2, W2tH, W2tL, DD);           // W2^T [n][k]
  // W12 = W1 @ W2 in split-f16 (BM=64 -> 128 blocks for occupancy)
  k_gemm16<64, false, 0><<<dim3(8, 16), blk, 0, stream>>>(W1sH, W1sL, DD, W2tH, W2tL, DD, B12H, B12L, DD, DD);
  k_tr16      <<<dim3(16, 16), blk, 0, stream>>>(B12H, B12tH, DD);              // W12^T planes
  k_tr16      <<<dim3(16, 16), blk, 0, stream>>>(B12L, B12tL, DD);
  k_symm_split<<<dim3(16, 16), blk, 0, stream>>>(R, BssH, BssL);
  k_splitT    <<<dim3(16, 16), blk, 0, stream>>>(W0, B0tH, B0tL, DD);           // W0^T
  k_split     <<<dim3(1024), blk, 0, stream>>>(W0, B0H, B0L);                   // W0 as-is
  k_splitT    <<<dim3(8, 8, 3), blk, 0, stream>>>(F, BFH, BFL, 512);            // F_i^T
  k_splitT    <<<dim3(8, 8, 3), blk, 0, stream>>>(G, BGH, BGL, 512);            // G_i^T
  k_pwi       <<<dim3(256), blk, 0, stream>>>(P, Wi, A2);
  k_pwo       <<<dim3(256), blk, 0, stream>>>(P, Wo, MoTH, MoTL);
  k_matvec    <<<dim3(256), blk, 0, stream>>>(P, bi, cvec);

  // ---- main pipeline ----
  k_in16<<<dim3(128, 16), blk, 0, stream>>>(x, A2, cvec, haH, haL);             // pre-rolled (-t), read-side roll

  // rotor 0 fwd (A pre-rolled, store +t)
  k_gemm16<128, false, +1><<<dim3(8, 64), blk, 0, stream>>>(haH, haL, DD, B0tH, B0tL, DD, hbH, hbL, DD, DD);
  // rotors 1,2 precomposed
  k_gemm16<128, false, 0><<<dim3(8, 64), blk, 0, stream>>>(hbH, hbL, DD, B12tH, B12tL, DD, haH, haL, DD, DD);
  // reversible blocks fwd (in place on ha; h2 = cols 512.., y1 = cols 0..)
  for (int i = 0; i < 3; ++i) {
    k_gemm16<64, true, 0><<<dim3(4, 128), blk, 0, stream>>>(haH + 512, haL + 512, DD, BFH + i * FGQ, BFL + i * FGQ, 512, haH, haL, DD, 512);
    k_gemm16<64, true, 0><<<dim3(4, 128), blk, 0, stream>>>(haH, haL, DD, BGH + i * FGQ, BGL + i * FGQ, 512, haH + 512, haL + 512, DD, 512);
  }
  // reflector
  k_gemm16<128, false, 0><<<dim3(8, 64), blk, 0, stream>>>(haH, haL, DD, BssH, BssL, DD, hbH, hbL, DD, DD);
  // reversible blocks reversed (in place on hb)
  for (int i = 2; i >= 0; --i) {
    k_gemm16<64, true, 0><<<dim3(4, 128), blk, 0, stream>>>(hbH + 512, hbL + 512, DD, BFH + i * FGQ, BFL + i * FGQ, 512, hbH, hbL, DD, 512);
    k_gemm16<64, true, 0><<<dim3(4, 128), blk, 0, stream>>>(hbH, hbL, DD, BGH + i * FGQ, BGL + i * FGQ, 512, hbH + 512, hbL + 512, DD, 512);
  }
  // rotors inverse: W12^T-mult (B = W12 as-is), store pre-rolled (-t)
  k_gemm16<128, false, -1><<<dim3(8, 64), blk, 0, stream>>>(hbH, hbL, DD, B12H, B12L, DD, haH, haL, DD, DD);
  // rotor 0 inverse: W0^T-mult (B = W0 as-is), store +t -> linear
  k_gemm16<128, false, +1><<<dim3(8, 64), blk, 0, stream>>>(haH, haL, DD, B0H, B0L, DD, hbH, hbL, DD, DD);

  // output projection (MFMA on already-split h planes)
  k_out_mfma<<<dim3(128), blk, 0, stream>>>(hbH, hbL, MoTH, MoTL, bo, out);
}

// Round 7
// 738.676 us; speedup vs baseline: 3.5244x; 1.0194x over previous
//
#include <hip/hip_runtime.h>
#include <math.h>

#define DD 1024
#define MM 8192   // B*S rows
#define SS 128
#define DINN 64
#define DOUTN 64

typedef _Float16 f16;
typedef _Float16 f16x8 __attribute__((ext_vector_type(8)));
typedef _Float16 f16x4 __attribute__((ext_vector_type(4)));
typedef float    f32x4 __attribute__((ext_vector_type(4)));

// direct global->LDS, 16B per lane; LDS base must be wave-uniform
#define GLOAD_LDS(g, l) \
  __builtin_amdgcn_global_load_lds((const __attribute__((address_space(1))) void*)(g), \
                                   (__attribute__((address_space(3))) void*)(l), 16, 0, 0)

// split helpers: store hi' = f16(y)*64, lo' = f16((y - hi)*64); y = hi'/64 + lo'/4096.
__device__ __forceinline__ void split_store(float y, f16* __restrict__ hp, f16* __restrict__ lp, size_t idx) {
  f16 h = (f16)y;
  hp[idx] = h * (f16)64.0f;
  lp[idx] = (f16)((y - (float)h) * 64.0f);
}
__device__ __forceinline__ float join_load(const f16* __restrict__ hp, const f16* __restrict__ lp, size_t idx) {
  return (float)hp[idx] * 0.015625f + (float)lp[idx] * 0.000244140625f;
}

// ---------------------------------------------------------------------------
// Split-f16 MFMA GEMM.  Y = (Ahi+Alo/64)(Bhi+Blo/64)/4096, terms HH+HL+LH.
// A planes [M][K] (lda), B planes [N][K] (ldb), C planes [M][ldc].
// BM in {128,64}; BN=128; BK=32; 256 thr / 4 waves.
// LDS per-plane tiles [rows][32] f16; 16B-chunk XOR swizzle s(row)=(row>>1)&3:
//   within any 8 consecutive lanes the (row parity, chunk) pairs cover all 8
//   slots -> ds_read_b128 frag reads hit all 32 banks exactly once (the old
//   s(row)=row&3 gave a guaranteed 2-way conflict: lanes l and l+4 same set).
// SHIFT: store col = (n + SHIFT*(m>>6)) & 1023 (scalar path only).
// EPI:  y = y_old + tanh(acc/4096).
// ---------------------------------------------------------------------------
template<int BM, bool EPI, int SHIFT>
__global__ __launch_bounds__(256)
void k_gemm16(const f16* __restrict__ Ahi, const f16* __restrict__ Alo, int lda,
              const f16* __restrict__ Bhi, const f16* __restrict__ Blo, int ldb,
              f16* __restrict__ Chi, f16* __restrict__ Clo, int ldc, int K) {
  constexpr int MT = BM / 32;      // 16x16 m-tiles per wave
  constexpr int AI = BM / 64;      // A staging iterations
  __shared__ f16 sA[2][2][BM * 32];
  __shared__ f16 sB[2][2][128 * 32];

  // XCD-aware swizzle (nwg % 8 == 0 for all our grids)
  const int nwg = gridDim.x * gridDim.y;
  int wg = blockIdx.y * gridDim.x + blockIdx.x;
  wg = (wg & 7) * (nwg >> 3) + (wg >> 3);
  const int bx = wg % gridDim.x, by = wg / gridDim.x;

  const int col0 = bx * 128, row0 = by * BM;
  const int u = threadIdx.x, lane = u & 63, wv = u >> 6;
  const int mh = (wv >> 1) * (BM >> 1);
  const int nh = (wv & 1) * 64;

  unsigned aoff[AI], boff[2];
  unsigned dstA[AI], dstB[2];
#pragma unroll
  for (int i = 0; i < AI; ++i) {
    const int P = i * 256 + u;
    const int row = P >> 2, kc = (P & 3) ^ ((row >> 1) & 3);
    aoff[i] = (unsigned)(row0 + row) * lda + kc * 8;
    dstA[i] = (i * 256 + wv * 64) * 8;
  }
#pragma unroll
  for (int i = 0; i < 2; ++i) {
    const int P = i * 256 + u;
    const int row = P >> 2, kc = (P & 3) ^ ((row >> 1) & 3);
    boff[i] = (unsigned)(col0 + row) * ldb + kc * 8;
    dstB[i] = (i * 256 + wv * 64) * 8;
  }

  // conflict-free frag chunk: (lane>>4) ^ s(row), s = (row>>1)&3, row=(lane&15)
  const int frag = (lane & 15) * 32 + (((lane >> 4) ^ ((lane >> 1) & 3)) * 8);

  f32x4 acc[MT][4];
#pragma unroll
  for (int i = 0; i < MT; ++i)
#pragma unroll
    for (int j = 0; j < 4; ++j) acc[i][j] = (f32x4){0.f, 0.f, 0.f, 0.f};

  auto stage = [&](int b, int k0) {
#pragma unroll
    for (int i = 0; i < AI; ++i) {
      GLOAD_LDS(Ahi + aoff[i] + k0, &sA[b][0][dstA[i]]);
      GLOAD_LDS(Alo + aoff[i] + k0, &sA[b][1][dstA[i]]);
    }
#pragma unroll
    for (int i = 0; i < 2; ++i) {
      GLOAD_LDS(Bhi + boff[i] + k0, &sB[b][0][dstB[i]]);
      GLOAD_LDS(Blo + boff[i] + k0, &sB[b][1][dstB[i]]);
    }
  };

  const int niter = K >> 5;
  stage(0, 0);
  __syncthreads();

  int buf = 0;
  for (int it = 0; it < niter; ++it) {
    if (it + 1 < niter) stage(buf ^ 1, (it + 1) << 5);
    f16x8 aH[MT], aL[MT], bH[4], bL[4];
#pragma unroll
    for (int mt = 0; mt < MT; ++mt) {
      aH[mt] = *(const f16x8*)&sA[buf][0][(mh + mt * 16) * 32 + frag];
      aL[mt] = *(const f16x8*)&sA[buf][1][(mh + mt * 16) * 32 + frag];
    }
#pragma unroll
    for (int nt = 0; nt < 4; ++nt) {
      bH[nt] = *(const f16x8*)&sB[buf][0][(nh + nt * 16) * 32 + frag];
      bL[nt] = *(const f16x8*)&sB[buf][1][(nh + nt * 16) * 32 + frag];
    }
#pragma unroll
    for (int mt = 0; mt < MT; ++mt)
#pragma unroll
      for (int nt = 0; nt < 4; ++nt) {
        acc[mt][nt] = __builtin_amdgcn_mfma_f32_16x16x32_f16(aH[mt], bH[nt], acc[mt][nt], 0, 0, 0);
        acc[mt][nt] = __builtin_amdgcn_mfma_f32_16x16x32_f16(aH[mt], bL[nt], acc[mt][nt], 0, 0, 0);
        acc[mt][nt] = __builtin_amdgcn_mfma_f32_16x16x32_f16(aL[mt], bH[nt], acc[mt][nt], 0, 0, 0);
      }
    __syncthreads();
    buf ^= 1;
  }

  if constexpr (SHIFT == 0) {
    // ---- vectorized epilogue: per-wave LDS transpose staging (reuse sB) ----
    f16* eH = ((f16*)sB) + wv * (16 * 84 * 2);
    f16* eL = eH + 16 * 84;
    const int lrow4 = (lane >> 4) << 2;
    const int lcol = lane & 15;
#pragma unroll
    for (int mt = 0; mt < MT; ++mt) {
#pragma unroll
      for (int nt = 0; nt < 4; ++nt) {
        const f32x4 a = acc[mt][nt];
#pragma unroll
        for (int r = 0; r < 4; ++r) {
          const float y = a[r] * 0.000244140625f;
          const f16 h = (f16)y;
          const int o = (lrow4 + r) * 84 + nt * 16 + lcol;
          eH[o] = h * (f16)64.0f;
          eL[o] = (f16)((y - (float)h) * 64.0f);
        }
      }
#pragma unroll
      for (int j = 0; j < 2; ++j) {
        const int idx = j * 64 + lane;
        const int row = idx >> 3, ch = idx & 7;
        const f16x8 vh = *(const f16x8*)&eH[row * 84 + ch * 8];
        const f16x8 vl = *(const f16x8*)&eL[row * 84 + ch * 8];
        const int m = row0 + mh + mt * 16 + row;
        const size_t gi = (size_t)m * ldc + col0 + nh + ch * 8;
        if (EPI) {
          const f16x8 oh = *(const f16x8*)&Chi[gi];
          const f16x8 ol = *(const f16x8*)&Clo[gi];
          f16x8 rh, rl;
#pragma unroll
          for (int q = 0; q < 8; ++q) {
            const float yn = (float)vh[q] * 0.015625f + (float)vl[q] * 0.000244140625f;
            const float y  = (float)oh[q] * 0.015625f + (float)ol[q] * 0.000244140625f + tanhf(yn);
            const f16 h = (f16)y;
            rh[q] = h * (f16)64.0f;
            rl[q] = (f16)((y - (float)h) * 64.0f);
          }
          *(f16x8*)&Chi[gi] = rh;
          *(f16x8*)&Clo[gi] = rl;
        } else {
          *(f16x8*)&Chi[gi] = vh;
          *(f16x8*)&Clo[gi] = vl;
        }
      }
    }
  } else {
    // ---- scalar epilogue (rotor shift folded into col index) ----
#pragma unroll
    for (int mt = 0; mt < MT; ++mt)
#pragma unroll
      for (int nt = 0; nt < 4; ++nt) {
        const f32x4 a = acc[mt][nt];
        const int n_base = col0 + nh + nt * 16 + (lane & 15);
#pragma unroll
        for (int r = 0; r < 4; ++r) {
          const int m = row0 + mh + mt * 16 + ((lane >> 4) << 2) + r;
          int n = (n_base + SHIFT * (m >> 6) + 2048) & (DD - 1);
          const size_t idx = (size_t)m * ldc + n;
          float y = a[r] * 0.000244140625f;
          if (EPI) y = join_load(Chi, Clo, idx) + tanhf(y);
          split_store(y, Chi, Clo, idx);
        }
      }
  }
}

// ---------------------------------------------------------------------------
// output projection as MFMA GEMM: out[b][t][c] = (h @ MoT^T)[r][c] + bo[c]
// A = h planes [8192][1024]; B = MoT planes [64][1024]; BM=64, grid 128.
// ---------------------------------------------------------------------------
__global__ __launch_bounds__(256)
void k_out_mfma(const f16* __restrict__ Ahi, const f16* __restrict__ Alo,
                const f16* __restrict__ Bhi, const f16* __restrict__ Blo,
                const float* __restrict__ bo, float* __restrict__ out) {
  __shared__ f16 sA[2][2][64 * 32];
  __shared__ f16 sB[2][2][64 * 32];
  const int row0 = blockIdx.x * 64;
  const int u = threadIdx.x, lane = u & 63, wv = u >> 6;
  const int mh = (wv >> 1) * 32, nh = (wv & 1) * 32;

  const int srow = u >> 2, skc = (u & 3) ^ ((srow >> 1) & 3);
  const unsigned aoff = (unsigned)(row0 + srow) * DD + skc * 8;
  const unsigned boff = (unsigned)srow * DD + skc * 8;
  const unsigned dst = (unsigned)(wv * 64) * 8;

  const int frag = (lane & 15) * 32 + (((lane >> 4) ^ ((lane >> 1) & 3)) * 8);

  f32x4 acc[2][2];
#pragma unroll
  for (int i = 0; i < 2; ++i)
#pragma unroll
    for (int j = 0; j < 2; ++j) acc[i][j] = (f32x4){0.f, 0.f, 0.f, 0.f};

  auto stage = [&](int b, int k0) {
    GLOAD_LDS(Ahi + aoff + k0, &sA[b][0][dst]);
    GLOAD_LDS(Alo + aoff + k0, &sA[b][1][dst]);
    GLOAD_LDS(Bhi + boff + k0, &sB[b][0][dst]);
    GLOAD_LDS(Blo + boff + k0, &sB[b][1][dst]);
  };

  stage(0, 0);
  __syncthreads();
  int buf = 0;
  for (int it = 0; it < 32; ++it) {
    if (it + 1 < 32) stage(buf ^ 1, (it + 1) << 5);
    f16x8 aH[2], aL[2], bH[2], bL[2];
#pragma unroll
    for (int mt = 0; mt < 2; ++mt) {
      aH[mt] = *(const f16x8*)&sA[buf][0][(mh + mt * 16) * 32 + frag];
      aL[mt] = *(const f16x8*)&sA[buf][1][(mh + mt * 16) * 32 + frag];
    }
#pragma unroll
    for (int nt = 0; nt < 2; ++nt) {
      bH[nt] = *(const f16x8*)&sB[buf][0][(nh + nt * 16) * 32 + frag];
      bL[nt] = *(const f16x8*)&sB[buf][1][(nh + nt * 16) * 32 + frag];
    }
#pragma unroll
    for (int mt = 0; mt < 2; ++mt)
#pragma unroll
      for (int nt = 0; nt < 2; ++nt) {
        acc[mt][nt] = __builtin_amdgcn_mfma_f32_16x16x32_f16(aH[mt], bH[nt], acc[mt][nt], 0, 0, 0);
        acc[mt][nt] = __builtin_amdgcn_mfma_f32_16x16x32_f16(aH[mt], bL[nt], acc[mt][nt], 0, 0, 0);
        acc[mt][nt] = __builtin_amdgcn_mfma_f32_16x16x32_f16(aL[mt], bH[nt], acc[mt][nt], 0, 0, 0);
      }
    __syncthreads();
    buf ^= 1;
  }

#pragma unroll
  for (int mt = 0; mt < 2; ++mt)
#pragma unroll
    for (int nt = 0; nt < 2; ++nt) {
      const f32x4 a = acc[mt][nt];
      const int c = nh + nt * 16 + (lane & 15);
      const float bias = bo[c];
#pragma unroll
      for (int r = 0; r < 4; ++r) {
        const int m = row0 + mh + mt * 16 + ((lane >> 4) << 2) + r;
        const int t = m >> 6, b = m & 63;
        out[((size_t)b * SS + t) * DOUTN + c] = a[r] * 0.000244140625f + bias;
      }
    }
}

// ---------------------------------------------------------------------------
// input projection, read-side roll: block covers ROLLED cols j in [c0,c0+64):
//   h[r][j] = sum_k x[b][t][k] * A2[(j+t)&1023][k] + cvec[(j+t)&1023]
// ---------------------------------------------------------------------------
__global__ __launch_bounds__(256)
void k_in16(const float* __restrict__ x, const float* __restrict__ A2,
            const float* __restrict__ cvec, f16* __restrict__ hH, f16* __restrict__ hL) {
  const int r0 = blockIdx.x * 64;         // 64 rows, t uniform per block
  const int c0 = blockIdx.y * 64;         // 64 rolled cols
  const int t = r0 >> 6;
  __shared__ float xs[64][65];
  __shared__ float a2s[64][67];
  __shared__ float cvs[64];
  const int u = threadIdx.x;
#pragma unroll
  for (int i = 0; i < 4; ++i) {
    const int idx = i * 256 + u;
    const int rr = idx >> 4, kc = (idx & 15) * 4;
    const float4 v = *(const float4*)&x[(size_t)rr * (SS * DINN) + t * DINN + kc];
    xs[rr][kc] = v.x; xs[rr][kc + 1] = v.y; xs[rr][kc + 2] = v.z; xs[rr][kc + 3] = v.w;
    const int src = (c0 + rr + t) & (DD - 1);
    const float4 a = *(const float4*)&A2[(size_t)src * DINN + kc];
    a2s[rr][kc] = a.x; a2s[rr][kc + 1] = a.y; a2s[rr][kc + 2] = a.z; a2s[rr][kc + 3] = a.w;
  }
  if (u < 64) cvs[u] = cvec[(c0 + u + t) & (DD - 1)];
  __syncthreads();
  const int rr = u >> 2;          // row 0..63 (4 lanes share a row)
  const int cg = (u & 3) * 16;    // col group
  float acc[16];
#pragma unroll
  for (int cc = 0; cc < 16; ++cc) acc[cc] = cvs[cg + cc];
  for (int k = 0; k < DINN; ++k) {
    const float xv = xs[rr][k];
#pragma unroll
    for (int cc = 0; cc < 16; ++cc) acc[cc] += xv * a2s[cg + cc][k];
  }
  const size_t base = (size_t)(r0 + rr) * DD + c0 + cg;
#pragma unroll
  for (int half = 0; half < 2; ++half) {
    f16x8 h8, l8;
#pragma unroll
    for (int q = 0; q < 8; ++q) {
      const float y = acc[half * 8 + q];
      const f16 h = (f16)y;
      h8[q] = h * (f16)64.0f;
      l8[q] = (f16)((y - (float)h) * 64.0f);
    }
    *(f16x8*)&hH[base + half * 8] = h8;
    *(f16x8*)&hL[base + half * 8] = l8;
  }
}

// ---------------------------------------------------------------------------
// precompute: splits / transposes
// ---------------------------------------------------------------------------
__global__ __launch_bounds__(256)
void k_split(const float* __restrict__ src, f16* __restrict__ hi, f16* __restrict__ lo) {
  const int i = blockIdx.x * 256 + threadIdx.x;
  const float4 v = ((const float4*)src)[i];
  f16x4 h4, l4;
  const float vv[4] = {v.x, v.y, v.z, v.w};
#pragma unroll
  for (int j = 0; j < 4; ++j) {
    f16 h = (f16)vv[j];
    h4[j] = h * (f16)64.0f;
    l4[j] = (f16)((vv[j] - (float)h) * 64.0f);
  }
  ((f16x4*)hi)[i] = h4;
  ((f16x4*)lo)[i] = l4;
}

// transpose + split: src fp32 [dim][dim] (z-batched) -> planes = src^T
__global__ __launch_bounds__(256)
void k_splitT(const float* __restrict__ src, f16* __restrict__ hi, f16* __restrict__ lo, int dim) {
  const size_t zo = (size_t)blockIdx.z * dim * dim;
  src += zo; hi += zo; lo += zo;
  const int i0 = blockIdx.y * 64, j0 = blockIdx.x * 64;
  __shared__ float tb[64][68];
  const int u = threadIdx.x;
#pragma unroll
  for (int it = 0; it < 4; ++it) {
    const int idx = it * 256 + u, rr = idx >> 4, cc = (idx & 15) * 4;
    *(float4*)&tb[rr][cc] = *(const float4*)&src[(size_t)(i0 + rr) * dim + j0 + cc];
  }
  __syncthreads();
#pragma unroll
  for (int it = 0; it < 4; ++it) {
    const int idx = it * 256 + u, rr = idx >> 4, cc = (idx & 15) * 4;
    f16x4 h4, l4;
#pragma unroll
    for (int j = 0; j < 4; ++j) {
      const float y = tb[cc + j][rr];
      f16 h = (f16)y;
      h4[j] = h * (f16)64.0f;
      l4[j] = (f16)((y - (float)h) * 64.0f);
    }
    const size_t o = (size_t)(j0 + rr) * dim + i0 + cc;
    *(f16x4*)&hi[o] = h4;
    *(f16x4*)&lo[o] = l4;
  }
}

// S = R + R^T, split-stored (symmetric => [n][k] fine)
__global__ __launch_bounds__(256)
void k_symm_split(const float* __restrict__ R, f16* __restrict__ hi, f16* __restrict__ lo) {
  const int i0 = blockIdx.y * 64, j0 = blockIdx.x * 64;
  __shared__ float tb[64][68];
  const int u = threadIdx.x;
#pragma unroll
  for (int it = 0; it < 4; ++it) {
    const int idx = it * 256 + u, rr = idx >> 4, cc = (idx & 15) * 4;
    *(float4*)&tb[rr][cc] = *(const float4*)&R[(size_t)(j0 + rr) * DD + i0 + cc];
  }
  __syncthreads();
#pragma unroll
  for (int it = 0; it < 4; ++it) {
    const int idx = it * 256 + u, rr = idx >> 4, cc = (idx & 15) * 4;
    const float4 v = *(const float4*)&R[(size_t)(i0 + rr) * DD + j0 + cc];
    const float vv[4] = {v.x + tb[cc + 0][rr], v.y + tb[cc + 1][rr],
                         v.z + tb[cc + 2][rr], v.w + tb[cc + 3][rr]};
    f16x4 h4, l4;
#pragma unroll
    for (int j = 0; j < 4; ++j) {
      f16 h = (f16)vv[j];
      h4[j] = h * (f16)64.0f;
      l4[j] = (f16)((vv[j] - (float)h) * 64.0f);
    }
    const size_t o = (size_t)(i0 + rr) * DD + j0 + cc;
    *(f16x4*)&hi[o] = h4;
    *(f16x4*)&lo[o] = l4;
  }
}

// f16 plane transpose
__global__ __launch_bounds__(256)
void k_tr16(const f16* __restrict__ in, f16* __restrict__ o, int dim) {
  const int i0 = blockIdx.y * 64, j0 = blockIdx.x * 64;
  __shared__ f16 tb[64][72];
  const int u = threadIdx.x;
#pragma unroll
  for (int it = 0; it < 2; ++it) {
    const int C = it * 256 + u, row = C >> 3, ch = C & 7;
    *(f16x8*)&tb[row][ch * 8] = *(const f16x8*)&in[(size_t)(i0 + row) * dim + j0 + ch * 8];
  }
  __syncthreads();
#pragma unroll
  for (int it = 0; it < 2; ++it) {
    const int C = it * 256 + u, row = C >> 3, ch = C & 7;
    f16x8 v;
#pragma unroll
    for (int j = 0; j < 8; ++j) v[j] = tb[ch * 8 + j][row];
    *(f16x8*)&o[(size_t)(j0 + row) * dim + i0 + ch * 8] = v;
  }
}

// A2 = P @ Wi  ([1024][64])
__global__ __launch_bounds__(256)
void k_pwi(const float* __restrict__ P, const float* __restrict__ Wi,
           float* __restrict__ A2) {
  const int m0 = blockIdx.x * 4;
  __shared__ float Ps[4][1024];
  const int u = threadIdx.x;
#pragma unroll
  for (int i = 0; i < 4; ++i) {
    const int idx = i * 256 + u, mi = idx >> 8, kc = (idx & 255) * 4;
    *(float4*)&Ps[mi][kc] = *(const float4*)&P[(size_t)(m0 + mi) * DD + kc];
  }
  __syncthreads();
  const int n = u & 63, mi = u >> 6;
  float acc = 0.f;
  for (int k = 0; k < DD; ++k) acc += Ps[mi][k] * Wi[(size_t)k * DINN + n];
  A2[(size_t)(m0 + mi) * DINN + n] = acc;
}

// MoT planes [c][d] = sum_k P[d][k] * Wo[c][k]   (split-stored transposed)
__global__ __launch_bounds__(256)
void k_pwo(const float* __restrict__ P, const float* __restrict__ Wo_,
           f16* __restrict__ MoTH, f16* __restrict__ MoTL) {
  const int d0 = blockIdx.x * 4;
  __shared__ float Ps[4][1024];
  __shared__ float ws[64][65];
  const int u = threadIdx.x;
#pragma unroll
  for (int i = 0; i < 4; ++i) {
    const int idx = i * 256 + u, mi = idx >> 8, kc = (idx & 255) * 4;
    *(float4*)&Ps[mi][kc] = *(const float4*)&P[(size_t)(d0 + mi) * DD + kc];
  }
  const int c = u & 63, di = u >> 6;
  float acc = 0.f;
  for (int k0 = 0; k0 < DD; k0 += 64) {
    __syncthreads();
#pragma unroll
    for (int i = 0; i < 4; ++i) {
      const int idx = i * 256 + u, cc = idx >> 4, kc = (idx & 15) * 4;
      const float4 v = *(const float4*)&Wo_[(size_t)cc * DD + k0 + kc];
      ws[cc][kc] = v.x; ws[cc][kc + 1] = v.y; ws[cc][kc + 2] = v.z; ws[cc][kc + 3] = v.w;
    }
    __syncthreads();
    for (int kk = 0; kk < 64; ++kk) acc += Ps[di][k0 + kk] * ws[c][kk];
  }
  split_store(acc, MoTH, MoTL, (size_t)c * DD + d0 + di);
}

// cvec = P @ bi ; wave per row
__global__ __launch_bounds__(256)
void k_matvec(const float* __restrict__ P, const float* __restrict__ b,
              float* __restrict__ c) {
  const int row = blockIdx.x * 4 + (threadIdx.x >> 6);
  const int l = threadIdx.x & 63;
  float s = 0.f;
  for (int k = l; k < DD; k += 64) s += P[(size_t)row * DD + k] * b[k];
  for (int o = 32; o; o >>= 1) s += __shfl_down(s, o, 64);
  if (l == 0) c[row] = s;
}

// ---------------------------------------------------------------------------
extern "C" void kernel_launch(void* const* d_in, const int* in_sizes, int n_in,
                              void* d_out, int out_size, void* d_ws, size_t ws_size,
                              hipStream_t stream) {
  (void)in_sizes; (void)n_in; (void)out_size; (void)ws_size;
  const float* x    = (const float*)d_in[0];
  const float* Wi   = (const float*)d_in[1];
  const float* bi   = (const float*)d_in[2];
  const float* P    = (const float*)d_in[3];
  const float* rotW = (const float*)d_in[4];
  const float* F    = (const float*)d_in[5];
  const float* G    = (const float*)d_in[6];
  const float* R    = (const float*)d_in[7];
  const float* Wo   = (const float*)d_in[8];
  const float* bo   = (const float*)d_in[9];
  float* out = (float*)d_out;
  char* w = (char*)d_ws;

  constexpr size_t MB = 1u << 20;
  // h planes (f16, [8192][1024], hi scaled x64, lo = resid x64)
  f16* haH = (f16*)(w + 0 * MB);
  f16* haL = (f16*)(w + 16 * MB);
  f16* hbH = (f16*)(w + 32 * MB);
  f16* hbL = (f16*)(w + 48 * MB);
  // weight planes ([n][k] layout)
  f16* B0tH = (f16*)(w + 64 * MB); f16* B0tL = (f16*)(w + 66 * MB);   // W0^T
  f16* B12tH= (f16*)(w + 68 * MB); f16* B12tL= (f16*)(w + 70 * MB);   // W12^T
  f16* BssH = (f16*)(w + 72 * MB); f16* BssL = (f16*)(w + 74 * MB);   // R+R^T
  f16* B12H = (f16*)(w + 76 * MB); f16* B12L = (f16*)(w + 78 * MB);   // W12
  f16* B0H  = (f16*)(w + 80 * MB); f16* B0L  = (f16*)(w + 82 * MB);   // W0
  f16* BFH  = (f16*)(w + 84 * MB); f16* BFL  = (f16*)(w + 85 * MB + 512 * 1024); // F^T x3
  f16* BGH  = (f16*)(w + 87 * MB); f16* BGL  = (f16*)(w + 88 * MB + 512 * 1024); // G^T x3
  // fp32/plane small
  float* A2   = (float*)(w + 90 * MB);
  f16* MoTH   = (f16*)(w + 90 * MB + 256 * 1024);
  f16* MoTL   = (f16*)(w + 90 * MB + 384 * 1024);
  float* cvec = (float*)(w + 90 * MB + 512 * 1024);
  // temp W1/W2 split planes alias hb region (dead until first GEMM writes hb)
  f16* W1sH = (f16*)(w + 32 * MB); f16* W1sL = (f16*)(w + 34 * MB);
  f16* W2tH = (f16*)(w + 36 * MB); f16* W2tL = (f16*)(w + 38 * MB);

  const float* W0 = rotW;
  const float* W1 = rotW + (1u << 20);
  const float* W2 = rotW + (2u << 20);

  const dim3 blk(256);
  const size_t FGQ = (size_t)512 * 512;

  // ---- precompute: weight splits ----
  k_split     <<<dim3(1024), blk, 0, stream>>>(W1, W1sH, W1sL);                 // W1 [m][k]
  k_splitT    <<<dim3(16, 16), blk, 0, stream>>>(W2, W2tH, W2tL, DD);           // W2^T [n][k]
  // W12 = W1 @ W2 in split-f16 (BM=64 -> 128 blocks for occupancy)
  k_gemm16<64, false, 0><<<dim3(8, 16), blk, 0, stream>>>(W1sH, W1sL, DD, W2tH, W2tL, DD, B12H, B12L, DD, DD);
  k_tr16      <<<dim3(16, 16), blk, 0, stream>>>(B12H, B12tH, DD);              // W12^T planes
  k_tr16      <<<dim3(16, 16), blk, 0, stream>>>(B12L, B12tL, DD);
  k_symm_split<<<dim3(16, 16), blk, 0, stream>>>(R, BssH, BssL);
  k_splitT    <<<dim3(16, 16), blk, 0, stream>>>(W0, B0tH, B0tL, DD);           // W0^T
  k_split     <<<dim3(1024), blk, 0, stream>>>(W0, B0H, B0L);                   // W0 as-is
  k_splitT    <<<dim3(8, 8, 3), blk, 0, stream>>>(F, BFH, BFL, 512);            // F_i^T
  k_splitT    <<<dim3(8, 8, 3), blk, 0, stream>>>(G, BGH, BGL, 512);            // G_i^T
  k_pwi       <<<dim3(256), blk, 0, stream>>>(P, Wi, A2);
  k_pwo       <<<dim3(256), blk, 0, stream>>>(P, Wo, MoTH, MoTL);
  k_matvec    <<<dim3(256), blk, 0, stream>>>(P, bi, cvec);

  // ---- main pipeline ----
  k_in16<<<dim3(128, 16), blk, 0, stream>>>(x, A2, cvec, haH, haL);             // pre-rolled (-t), read-side roll

  // rotor 0 fwd (A pre-rolled, store +t)
  k_gemm16<128, false, +1><<<dim3(8, 64), blk, 0, stream>>>(haH, haL, DD, B0tH, B0tL, DD, hbH, hbL, DD, DD);
  // rotors 1,2 precomposed
  k_gemm16<128, false, 0><<<dim3(8, 64), blk, 0, stream>>>(hbH, hbL, DD, B12tH, B12tL, DD, haH, haL, DD, DD);
  // reversible blocks fwd (in place on ha; h2 = cols 512.., y1 = cols 0..)
  for (int i = 0; i < 3; ++i) {
    k_gemm16<64, true, 0><<<dim3(4, 128), blk, 0, stream>>>(haH + 512, haL + 512, DD, BFH + i * FGQ, BFL + i * FGQ, 512, haH, haL, DD, 512);
    k_gemm16<64, true, 0><<<dim3(4, 128), blk, 0, stream>>>(haH, haL, DD, BGH + i * FGQ, BGL + i * FGQ, 512, haH + 512, haL + 512, DD, 512);
  }
  // reflector
  k_gemm16<128, false, 0><<<dim3(8, 64), blk, 0, stream>>>(haH, haL, DD, BssH, BssL, DD, hbH, hbL, DD, DD);
  // reversible blocks reversed (in place on hb)
  for (int i = 2; i >= 0; --i) {
    k_gemm16<64, true, 0><<<dim3(4, 128), blk, 0, stream>>>(hbH + 512, hbL + 512, DD, BFH + i * FGQ, BFL + i * FGQ, 512, hbH, hbL, DD, 512);
    k_gemm16<64, true, 0><<<dim3(4, 128), blk, 0, stream>>>(hbH, hbL, DD, BGH + i * FGQ, BGL + i * FGQ, 512, hbH + 512, hbL + 512, DD, 512);
  }
  // rotors inverse: W12^T-mult (B = W12 as-is), store pre-rolled (-t)
  k_gemm16<128, false, -1><<<dim3(8, 64), blk, 0, stream>>>(hbH, hbL, DD, B12H, B12L, DD, haH, haL, DD, DD);
  // rotor 0 inverse: W0^T-mult (B = W0 as-is), store +t -> linear
  k_gemm16<128, false, +1><<<dim3(8, 64), blk, 0, stream>>>(haH, haL, DD, B0H, B0L, DD, hbH, hbL, DD, DD);

  // output projection (MFMA on already-split h planes)
  k_out_mfma<<<dim3(128), blk, 0, stream>>>(hbH, hbL, MoTH, MoTL, bo, out);
}

// Round 8
// 706.999 us; speedup vs baseline: 3.6823x; 1.0448x over previous
//
#include <hip/hip_runtime.h>
#include <math.h>

#define DD 1024
#define MM 8192   // B*S rows
#define SS 128
#define DINN 64
#define DOUTN 64

typedef _Float16 f16;
typedef _Float16 f16x8 __attribute__((ext_vector_type(8)));
typedef _Float16 f16x4 __attribute__((ext_vector_type(4)));
typedef float    f32x4 __attribute__((ext_vector_type(4)));

// direct global->LDS, 16B per lane; LDS base must be wave-uniform
#define GLOAD_LDS(g, l) \
  __builtin_amdgcn_global_load_lds((const __attribute__((address_space(1))) void*)(g), \
                                   (__attribute__((address_space(3))) void*)(l), 16, 0, 0)

// split helpers: store hi' = f16(y)*64, lo' = f16((y - hi)*64); y = hi'/64 + lo'/4096.
__device__ __forceinline__ void split_store(float y, f16* __restrict__ hp, f16* __restrict__ lp, size_t idx) {
  f16 h = (f16)y;
  hp[idx] = h * (f16)64.0f;
  lp[idx] = (f16)((y - (float)h) * 64.0f);
}
__device__ __forceinline__ float join_load(const f16* __restrict__ hp, const f16* __restrict__ lp, size_t idx) {
  return (float)hp[idx] * 0.015625f + (float)lp[idx] * 0.000244140625f;
}

// ---------------------------------------------------------------------------
// Split-f16 MFMA GEMM.  Y = (Ahi+Alo/64)(Bhi+Blo/64)/4096, terms HH+HL+LH.
// A planes [M][K] (lda), B planes [N][K] (ldb), C planes [M][ldc].
// BM in {128,64}; BN=128; BK=32; 256 thr / 4 waves.
// LDS per-plane tiles [rows][32] f16; 16B-chunk XOR swizzle s(row)=(row>>1)&3
// (conflict-free b128 frag reads; verified R7: SQ_LDS_BANK_CONFLICT = 0).
// SHIFT: store col = (n + SHIFT*(m>>6)) & 1023 (scalar path only).
// EPI:  y = y_old + tanh(acc/4096).
// ---------------------------------------------------------------------------
template<int BM, bool EPI, int SHIFT>
__global__ __launch_bounds__(256)
void k_gemm16(const f16* __restrict__ Ahi, const f16* __restrict__ Alo, int lda,
              const f16* __restrict__ Bhi, const f16* __restrict__ Blo, int ldb,
              f16* __restrict__ Chi, f16* __restrict__ Clo, int ldc, int K) {
  constexpr int MT = BM / 32;      // 16x16 m-tiles per wave
  constexpr int AI = BM / 64;      // A staging iterations
  __shared__ f16 sA[2][2][BM * 32];
  __shared__ f16 sB[2][2][128 * 32];

  // XCD-aware swizzle (nwg % 8 == 0 for all our grids)
  const int nwg = gridDim.x * gridDim.y;
  int wg = blockIdx.y * gridDim.x + blockIdx.x;
  wg = (wg & 7) * (nwg >> 3) + (wg >> 3);
  const int bx = wg % gridDim.x, by = wg / gridDim.x;

  const int col0 = bx * 128, row0 = by * BM;
  const int u = threadIdx.x, lane = u & 63, wv = u >> 6;
  const int mh = (wv >> 1) * (BM >> 1);
  const int nh = (wv & 1) * 64;

  unsigned aoff[AI], boff[2];
  unsigned dstA[AI], dstB[2];
#pragma unroll
  for (int i = 0; i < AI; ++i) {
    const int P = i * 256 + u;
    const int row = P >> 2, kc = (P & 3) ^ ((row >> 1) & 3);
    aoff[i] = (unsigned)(row0 + row) * lda + kc * 8;
    dstA[i] = (i * 256 + wv * 64) * 8;
  }
#pragma unroll
  for (int i = 0; i < 2; ++i) {
    const int P = i * 256 + u;
    const int row = P >> 2, kc = (P & 3) ^ ((row >> 1) & 3);
    boff[i] = (unsigned)(col0 + row) * ldb + kc * 8;
    dstB[i] = (i * 256 + wv * 64) * 8;
  }

  // conflict-free frag chunk: (lane>>4) ^ s(row), s = (row>>1)&3, row=(lane&15)
  const int frag = (lane & 15) * 32 + (((lane >> 4) ^ ((lane >> 1) & 3)) * 8);

  f32x4 acc[MT][4];
#pragma unroll
  for (int i = 0; i < MT; ++i)
#pragma unroll
    for (int j = 0; j < 4; ++j) acc[i][j] = (f32x4){0.f, 0.f, 0.f, 0.f};

  auto stage = [&](int b, int k0) {
#pragma unroll
    for (int i = 0; i < AI; ++i) {
      GLOAD_LDS(Ahi + aoff[i] + k0, &sA[b][0][dstA[i]]);
      GLOAD_LDS(Alo + aoff[i] + k0, &sA[b][1][dstA[i]]);
    }
#pragma unroll
    for (int i = 0; i < 2; ++i) {
      GLOAD_LDS(Bhi + boff[i] + k0, &sB[b][0][dstB[i]]);
      GLOAD_LDS(Blo + boff[i] + k0, &sB[b][1][dstB[i]]);
    }
  };

  const int niter = K >> 5;
  stage(0, 0);
  __syncthreads();

  int buf = 0;
  for (int it = 0; it < niter; ++it) {
    if (it + 1 < niter) stage(buf ^ 1, (it + 1) << 5);
    f16x8 aH[MT], aL[MT], bH[4], bL[4];
#pragma unroll
    for (int mt = 0; mt < MT; ++mt) {
      aH[mt] = *(const f16x8*)&sA[buf][0][(mh + mt * 16) * 32 + frag];
      aL[mt] = *(const f16x8*)&sA[buf][1][(mh + mt * 16) * 32 + frag];
    }
#pragma unroll
    for (int nt = 0; nt < 4; ++nt) {
      bH[nt] = *(const f16x8*)&sB[buf][0][(nh + nt * 16) * 32 + frag];
      bL[nt] = *(const f16x8*)&sB[buf][1][(nh + nt * 16) * 32 + frag];
    }
#pragma unroll
    for (int mt = 0; mt < MT; ++mt)
#pragma unroll
      for (int nt = 0; nt < 4; ++nt) {
        acc[mt][nt] = __builtin_amdgcn_mfma_f32_16x16x32_f16(aH[mt], bH[nt], acc[mt][nt], 0, 0, 0);
        acc[mt][nt] = __builtin_amdgcn_mfma_f32_16x16x32_f16(aH[mt], bL[nt], acc[mt][nt], 0, 0, 0);
        acc[mt][nt] = __builtin_amdgcn_mfma_f32_16x16x32_f16(aL[mt], bH[nt], acc[mt][nt], 0, 0, 0);
      }
    __syncthreads();
    buf ^= 1;
  }

  if constexpr (SHIFT == 0) {
    // ---- vectorized epilogue: per-wave LDS transpose staging (reuse sB) ----
    f16* eH = ((f16*)sB) + wv * (16 * 84 * 2);
    f16* eL = eH + 16 * 84;
    const int lrow4 = (lane >> 4) << 2;
    const int lcol = lane & 15;
#pragma unroll
    for (int mt = 0; mt < MT; ++mt) {
#pragma unroll
      for (int nt = 0; nt < 4; ++nt) {
        const f32x4 a = acc[mt][nt];
#pragma unroll
        for (int r = 0; r < 4; ++r) {
          const float y = a[r] * 0.000244140625f;
          const f16 h = (f16)y;
          const int o = (lrow4 + r) * 84 + nt * 16 + lcol;
          eH[o] = h * (f16)64.0f;
          eL[o] = (f16)((y - (float)h) * 64.0f);
        }
      }
#pragma unroll
      for (int j = 0; j < 2; ++j) {
        const int idx = j * 64 + lane;
        const int row = idx >> 3, ch = idx & 7;
        const f16x8 vh = *(const f16x8*)&eH[row * 84 + ch * 8];
        const f16x8 vl = *(const f16x8*)&eL[row * 84 + ch * 8];
        const int m = row0 + mh + mt * 16 + row;
        const size_t gi = (size_t)m * ldc + col0 + nh + ch * 8;
        if (EPI) {
          const f16x8 oh = *(const f16x8*)&Chi[gi];
          const f16x8 ol = *(const f16x8*)&Clo[gi];
          f16x8 rh, rl;
#pragma unroll
          for (int q = 0; q < 8; ++q) {
            const float yn = (float)vh[q] * 0.015625f + (float)vl[q] * 0.000244140625f;
            const float y  = (float)oh[q] * 0.015625f + (float)ol[q] * 0.000244140625f + tanhf(yn);
            const f16 h = (f16)y;
            rh[q] = h * (f16)64.0f;
            rl[q] = (f16)((y - (float)h) * 64.0f);
          }
          *(f16x8*)&Chi[gi] = rh;
          *(f16x8*)&Clo[gi] = rl;
        } else {
          *(f16x8*)&Chi[gi] = vh;
          *(f16x8*)&Clo[gi] = vl;
        }
      }
    }
  } else {
    // ---- scalar epilogue (rotor shift folded into col index) ----
#pragma unroll
    for (int mt = 0; mt < MT; ++mt)
#pragma unroll
      for (int nt = 0; nt < 4; ++nt) {
        const f32x4 a = acc[mt][nt];
        const int n_base = col0 + nh + nt * 16 + (lane & 15);
#pragma unroll
        for (int r = 0; r < 4; ++r) {
          const int m = row0 + mh + mt * 16 + ((lane >> 4) << 2) + r;
          int n = (n_base + SHIFT * (m >> 6) + 2048) & (DD - 1);
          const size_t idx = (size_t)m * ldc + n;
          float y = a[r] * 0.000244140625f;
          if (EPI) y = join_load(Chi, Clo, idx) + tanhf(y);
          split_store(y, Chi, Clo, idx);
        }
      }
  }
}

// ---------------------------------------------------------------------------
// input projection as MFMA GEMM (replaces the 59 µs LDS-bound VALU version):
//   h0_pre[r][j] = sum_k x[b][t][k]*A2[(j+t)&1023][k] + cvec[(j+t)&1023]
//   (r = t*64+b; t = blockIdx.y uniform since BM=64)
// A = x split planes, natural [b][t][k] layout — the r-reorder is folded into
// per-lane gload SOURCE addresses. B = A2 split planes [1024][64]; the roll is
// row-granular on the B staging source. K=64 (2 BK-iters). BM=64 x BN=128.
// ---------------------------------------------------------------------------
__global__ __launch_bounds__(256)
void k_in_mfma(const f16* __restrict__ xH, const f16* __restrict__ xL,
               const f16* __restrict__ A2H, const f16* __restrict__ A2L,
               const float* __restrict__ cvec,
               f16* __restrict__ hH, f16* __restrict__ hL) {
  __shared__ f16 sA[2][2][64 * 32];
  __shared__ f16 sB[2][2][128 * 32];
  const int bx = blockIdx.x, by = blockIdx.y;   // n-block, m-block(=t)
  const int col0 = bx * 128, row0 = by * 64, t = by;
  const int u = threadIdx.x, lane = u & 63, wv = u >> 6;
  const int mh = (wv >> 1) * 32;
  const int nh = (wv & 1) * 64;

  // A staging: row = b (0..63); x addr = (b*SS + t)*DINN + k
  unsigned aoff, boff[2], dstA, dstB[2];
  {
    const int row = u >> 2, kc = (u & 3) ^ ((row >> 1) & 3);
    aoff = (unsigned)(row * SS + t) * DINN + kc * 8;
    dstA = (unsigned)(wv * 64) * 8;
  }
#pragma unroll
  for (int i = 0; i < 2; ++i) {
    const int P = i * 256 + u;
    const int row = P >> 2, kc = (P & 3) ^ ((row >> 1) & 3);
    const int src = (col0 + row + t) & (DD - 1);
    boff[i] = (unsigned)src * DINN + kc * 8;
    dstB[i] = (i * 256 + wv * 64) * 8;
  }

  const int frag = (lane & 15) * 32 + (((lane >> 4) ^ ((lane >> 1) & 3)) * 8);

  f32x4 acc[2][4];
#pragma unroll
  for (int i = 0; i < 2; ++i)
#pragma unroll
    for (int j = 0; j < 4; ++j) acc[i][j] = (f32x4){0.f, 0.f, 0.f, 0.f};

  auto stage = [&](int b, int k0) {
    GLOAD_LDS(xH + aoff + k0, &sA[b][0][dstA]);
    GLOAD_LDS(xL + aoff + k0, &sA[b][1][dstA]);
#pragma unroll
    for (int i = 0; i < 2; ++i) {
      GLOAD_LDS(A2H + boff[i] + k0, &sB[b][0][dstB[i]]);
      GLOAD_LDS(A2L + boff[i] + k0, &sB[b][1][dstB[i]]);
    }
  };

  stage(0, 0);
  __syncthreads();
  int buf = 0;
#pragma unroll
  for (int it = 0; it < 2; ++it) {
    if (it == 0) stage(1, 32);
    f16x8 aH[2], aL[2], bH[4], bL[4];
#pragma unroll
    for (int mt = 0; mt < 2; ++mt) {
      aH[mt] = *(const f16x8*)&sA[buf][0][(mh + mt * 16) * 32 + frag];
      aL[mt] = *(const f16x8*)&sA[buf][1][(mh + mt * 16) * 32 + frag];
    }
#pragma unroll
    for (int nt = 0; nt < 4; ++nt) {
      bH[nt] = *(const f16x8*)&sB[buf][0][(nh + nt * 16) * 32 + frag];
      bL[nt] = *(const f16x8*)&sB[buf][1][(nh + nt * 16) * 32 + frag];
    }
#pragma unroll
    for (int mt = 0; mt < 2; ++mt)
#pragma unroll
      for (int nt = 0; nt < 4; ++nt) {
        acc[mt][nt] = __builtin_amdgcn_mfma_f32_16x16x32_f16(aH[mt], bH[nt], acc[mt][nt], 0, 0, 0);
        acc[mt][nt] = __builtin_amdgcn_mfma_f32_16x16x32_f16(aH[mt], bL[nt], acc[mt][nt], 0, 0, 0);
        acc[mt][nt] = __builtin_amdgcn_mfma_f32_16x16x32_f16(aL[mt], bH[nt], acc[mt][nt], 0, 0, 0);
      }
    __syncthreads();
    buf ^= 1;
  }

  // add rolled cvec bias in-register, then vectorized split-store
  f16* eH = ((f16*)sB) + wv * (16 * 84 * 2);
  f16* eL = eH + 16 * 84;
  const int lrow4 = (lane >> 4) << 2;
  const int lcol = lane & 15;
#pragma unroll
  for (int mt = 0; mt < 2; ++mt) {
#pragma unroll
    for (int nt = 0; nt < 4; ++nt) {
      const f32x4 a = acc[mt][nt];
      const int n = col0 + nh + nt * 16 + lcol;
      const float cv = cvec[(n + t) & (DD - 1)];
#pragma unroll
      for (int r = 0; r < 4; ++r) {
        const float y = a[r] * 0.000244140625f + cv;
        const f16 h = (f16)y;
        const int o = (lrow4 + r) * 84 + nt * 16 + lcol;
        eH[o] = h * (f16)64.0f;
        eL[o] = (f16)((y - (float)h) * 64.0f);
      }
    }
#pragma unroll
    for (int j = 0; j < 2; ++j) {
      const int idx = j * 64 + lane;
      const int row = idx >> 3, ch = idx & 7;
      const f16x8 vh = *(const f16x8*)&eH[row * 84 + ch * 8];
      const f16x8 vl = *(const f16x8*)&eL[row * 84 + ch * 8];
      const int m = row0 + mh + mt * 16 + row;
      const size_t gi = (size_t)m * DD + col0 + nh + ch * 8;
      *(f16x8*)&hH[gi] = vh;
      *(f16x8*)&hL[gi] = vl;
    }
  }
}

// ---------------------------------------------------------------------------
// output projection as MFMA GEMM: out[b][t][c] = (h @ MoT^T)[r][c] + bo[c]
// ---------------------------------------------------------------------------
__global__ __launch_bounds__(256)
void k_out_mfma(const f16* __restrict__ Ahi, const f16* __restrict__ Alo,
                const f16* __restrict__ Bhi, const f16* __restrict__ Blo,
                const float* __restrict__ bo, float* __restrict__ out) {
  __shared__ f16 sA[2][2][64 * 32];
  __shared__ f16 sB[2][2][64 * 32];
  const int row0 = blockIdx.x * 64;
  const int u = threadIdx.x, lane = u & 63, wv = u >> 6;
  const int mh = (wv >> 1) * 32, nh = (wv & 1) * 32;

  const int srow = u >> 2, skc = (u & 3) ^ ((srow >> 1) & 3);
  const unsigned aoff = (unsigned)(row0 + srow) * DD + skc * 8;
  const unsigned boff = (unsigned)srow * DD + skc * 8;
  const unsigned dst = (unsigned)(wv * 64) * 8;

  const int frag = (lane & 15) * 32 + (((lane >> 4) ^ ((lane >> 1) & 3)) * 8);

  f32x4 acc[2][2];
#pragma unroll
  for (int i = 0; i < 2; ++i)
#pragma unroll
    for (int j = 0; j < 2; ++j) acc[i][j] = (f32x4){0.f, 0.f, 0.f, 0.f};

  auto stage = [&](int b, int k0) {
    GLOAD_LDS(Ahi + aoff + k0, &sA[b][0][dst]);
    GLOAD_LDS(Alo + aoff + k0, &sA[b][1][dst]);
    GLOAD_LDS(Bhi + boff + k0, &sB[b][0][dst]);
    GLOAD_LDS(Blo + boff + k0, &sB[b][1][dst]);
  };

  stage(0, 0);
  __syncthreads();
  int buf = 0;
  for (int it = 0; it < 32; ++it) {
    if (it + 1 < 32) stage(buf ^ 1, (it + 1) << 5);
    f16x8 aH[2], aL[2], bH[2], bL[2];
#pragma unroll
    for (int mt = 0; mt < 2; ++mt) {
      aH[mt] = *(const f16x8*)&sA[buf][0][(mh + mt * 16) * 32 + frag];
      aL[mt] = *(const f16x8*)&sA[buf][1][(mh + mt * 16) * 32 + frag];
    }
#pragma unroll
    for (int nt = 0; nt < 2; ++nt) {
      bH[nt] = *(const f16x8*)&sB[buf][0][(nh + nt * 16) * 32 + frag];
      bL[nt] = *(const f16x8*)&sB[buf][1][(nh + nt * 16) * 32 + frag];
    }
#pragma unroll
    for (int mt = 0; mt < 2; ++mt)
#pragma unroll
      for (int nt = 0; nt < 2; ++nt) {
        acc[mt][nt] = __builtin_amdgcn_mfma_f32_16x16x32_f16(aH[mt], bH[nt], acc[mt][nt], 0, 0, 0);
        acc[mt][nt] = __builtin_amdgcn_mfma_f32_16x16x32_f16(aH[mt], bL[nt], acc[mt][nt], 0, 0, 0);
        acc[mt][nt] = __builtin_amdgcn_mfma_f32_16x16x32_f16(aL[mt], bH[nt], acc[mt][nt], 0, 0, 0);
      }
    __syncthreads();
    buf ^= 1;
  }

#pragma unroll
  for (int mt = 0; mt < 2; ++mt)
#pragma unroll
    for (int nt = 0; nt < 2; ++nt) {
      const f32x4 a = acc[mt][nt];
      const int c = nh + nt * 16 + (lane & 15);
      const float bias = bo[c];
#pragma unroll
      for (int r = 0; r < 4; ++r) {
        const int m = row0 + mh + mt * 16 + ((lane >> 4) << 2) + r;
        const int t = m >> 6, b = m & 63;
        out[((size_t)b * SS + t) * DOUTN + c] = a[r] * 0.000244140625f + bias;
      }
    }
}

// ---------------------------------------------------------------------------
// precompute: splits / transposes
// ---------------------------------------------------------------------------
__global__ __launch_bounds__(256)
void k_split(const float* __restrict__ src, f16* __restrict__ hi, f16* __restrict__ lo) {
  const int i = blockIdx.x * 256 + threadIdx.x;
  const float4 v = ((const float4*)src)[i];
  f16x4 h4, l4;
  const float vv[4] = {v.x, v.y, v.z, v.w};
#pragma unroll
  for (int j = 0; j < 4; ++j) {
    f16 h = (f16)vv[j];
    h4[j] = h * (f16)64.0f;
    l4[j] = (f16)((vv[j] - (float)h) * 64.0f);
  }
  ((f16x4*)hi)[i] = h4;
  ((f16x4*)lo)[i] = l4;
}

// transpose + split: src fp32 [dim][dim] (z-batched) -> planes = src^T
__global__ __launch_bounds__(256)
void k_splitT(const float* __restrict__ src, f16* __restrict__ hi, f16* __restrict__ lo, int dim) {
  const size_t zo = (size_t)blockIdx.z * dim * dim;
  src += zo; hi += zo; lo += zo;
  const int i0 = blockIdx.y * 64, j0 = blockIdx.x * 64;
  __shared__ float tb[64][68];
  const int u = threadIdx.x;
#pragma unroll
  for (int it = 0; it < 4; ++it) {
    const int idx = it * 256 + u, rr = idx >> 4, cc = (idx & 15) * 4;
    *(float4*)&tb[rr][cc] = *(const float4*)&src[(size_t)(i0 + rr) * dim + j0 + cc];
  }
  __syncthreads();
#pragma unroll
  for (int it = 0; it < 4; ++it) {
    const int idx = it * 256 + u, rr = idx >> 4, cc = (idx & 15) * 4;
    f16x4 h4, l4;
#pragma unroll
    for (int j = 0; j < 4; ++j) {
      const float y = tb[cc + j][rr];
      f16 h = (f16)y;
      h4[j] = h * (f16)64.0f;
      l4[j] = (f16)((y - (float)h) * 64.0f);
    }
    const size_t o = (size_t)(j0 + rr) * dim + i0 + cc;
    *(f16x4*)&hi[o] = h4;
    *(f16x4*)&lo[o] = l4;
  }
}

// S = R + R^T, split-stored (symmetric => [n][k] fine)
__global__ __launch_bounds__(256)
void k_symm_split(const float* __restrict__ R, f16* __restrict__ hi, f16* __restrict__ lo) {
  const int i0 = blockIdx.y * 64, j0 = blockIdx.x * 64;
  __shared__ float tb[64][68];
  const int u = threadIdx.x;
#pragma unroll
  for (int it = 0; it < 4; ++it) {
    const int idx = it * 256 + u, rr = idx >> 4, cc = (idx & 15) * 4;
    *(float4*)&tb[rr][cc] = *(const float4*)&R[(size_t)(j0 + rr) * DD + i0 + cc];
  }
  __syncthreads();
#pragma unroll
  for (int it = 0; it < 4; ++it) {
    const int idx = it * 256 + u, rr = idx >> 4, cc = (idx & 15) * 4;
    const float4 v = *(const float4*)&R[(size_t)(i0 + rr) * DD + j0 + cc];
    const float vv[4] = {v.x + tb[cc + 0][rr], v.y + tb[cc + 1][rr],
                         v.z + tb[cc + 2][rr], v.w + tb[cc + 3][rr]};
    f16x4 h4, l4;
#pragma unroll
    for (int j = 0; j < 4; ++j) {
      f16 h = (f16)vv[j];
      h4[j] = h * (f16)64.0f;
      l4[j] = (f16)((vv[j] - (float)h) * 64.0f);
    }
    const size_t o = (size_t)(i0 + rr) * DD + j0 + cc;
    *(f16x4*)&hi[o] = h4;
    *(f16x4*)&lo[o] = l4;
  }
}

// f16 plane transpose
__global__ __launch_bounds__(256)
void k_tr16(const f16* __restrict__ in, f16* __restrict__ o, int dim) {
  const int i0 = blockIdx.y * 64, j0 = blockIdx.x * 64;
  __shared__ f16 tb[64][72];
  const int u = threadIdx.x;
#pragma unroll
  for (int it = 0; it < 2; ++it) {
    const int C = it * 256 + u, row = C >> 3, ch = C & 7;
    *(f16x8*)&tb[row][ch * 8] = *(const f16x8*)&in[(size_t)(i0 + row) * dim + j0 + ch * 8];
  }
  __syncthreads();
#pragma unroll
  for (int it = 0; it < 2; ++it) {
    const int C = it * 256 + u, row = C >> 3, ch = C & 7;
    f16x8 v;
#pragma unroll
    for (int j = 0; j < 8; ++j) v[j] = tb[ch * 8 + j][row];
    *(f16x8*)&o[(size_t)(j0 + row) * dim + i0 + ch * 8] = v;
  }
}

// A2 planes = split(P @ Wi)  ([1024][64])
__global__ __launch_bounds__(256)
void k_pwi(const float* __restrict__ P, const float* __restrict__ Wi,
           f16* __restrict__ A2H, f16* __restrict__ A2L) {
  const int m0 = blockIdx.x * 4;
  __shared__ float Ps[4][1024];
  const int u = threadIdx.x;
#pragma unroll
  for (int i = 0; i < 4; ++i) {
    const int idx = i * 256 + u, mi = idx >> 8, kc = (idx & 255) * 4;
    *(float4*)&Ps[mi][kc] = *(const float4*)&P[(size_t)(m0 + mi) * DD + kc];
  }
  __syncthreads();
  const int n = u & 63, mi = u >> 6;
  float acc = 0.f;
  for (int k = 0; k < DD; ++k) acc += Ps[mi][k] * Wi[(size_t)k * DINN + n];
  split_store(acc, A2H, A2L, (size_t)(m0 + mi) * DINN + n);
}

// MoT planes [c][d] = sum_k P[d][k] * Wo[c][k]   (split-stored transposed)
__global__ __launch_bounds__(256)
void k_pwo(const float* __restrict__ P, const float* __restrict__ Wo_,
           f16* __restrict__ MoTH, f16* __restrict__ MoTL) {
  const int d0 = blockIdx.x * 4;
  __shared__ float Ps[4][1024];
  __shared__ float ws[64][65];
  const int u = threadIdx.x;
#pragma unroll
  for (int i = 0; i < 4; ++i) {
    const int idx = i * 256 + u, mi = idx >> 8, kc = (idx & 255) * 4;
    *(float4*)&Ps[mi][kc] = *(const float4*)&P[(size_t)(d0 + mi) * DD + kc];
  }
  const int c = u & 63, di = u >> 6;
  float acc = 0.f;
  for (int k0 = 0; k0 < DD; k0 += 64) {
    __syncthreads();
#pragma unroll
    for (int i = 0; i < 4; ++i) {
      const int idx = i * 256 + u, cc = idx >> 4, kc = (idx & 15) * 4;
      const float4 v = *(const float4*)&Wo_[(size_t)cc * DD + k0 + kc];
      ws[cc][kc] = v.x; ws[cc][kc + 1] = v.y; ws[cc][kc + 2] = v.z; ws[cc][kc + 3] = v.w;
    }
    __syncthreads();
    for (int kk = 0; kk < 64; ++kk) acc += Ps[di][k0 + kk] * ws[c][kk];
  }
  split_store(acc, MoTH, MoTL, (size_t)c * DD + d0 + di);
}

// cvec = P @ bi ; wave per row
__global__ __launch_bounds__(256)
void k_matvec(const float* __restrict__ P, const float* __restrict__ b,
              float* __restrict__ c) {
  const int row = blockIdx.x * 4 + (threadIdx.x >> 6);
  const int l = threadIdx.x & 63;
  float s = 0.f;
  for (int k = l; k < DD; k += 64) s += P[(size_t)row * DD + k] * b[k];
  for (int o = 32; o; o >>= 1) s += __shfl_down(s, o, 64);
  if (l == 0) c[row] = s;
}

// ---------------------------------------------------------------------------
extern "C" void kernel_launch(void* const* d_in, const int* in_sizes, int n_in,
                              void* d_out, int out_size, void* d_ws, size_t ws_size,
                              hipStream_t stream) {
  (void)in_sizes; (void)n_in; (void)out_size; (void)ws_size;
  const float* x    = (const float*)d_in[0];
  const float* Wi   = (const float*)d_in[1];
  const float* bi   = (const float*)d_in[2];
  const float* P    = (const float*)d_in[3];
  const float* rotW = (const float*)d_in[4];
  const float* F    = (const float*)d_in[5];
  const float* G    = (const float*)d_in[6];
  const float* R    = (const float*)d_in[7];
  const float* Wo   = (const float*)d_in[8];
  const float* bo   = (const float*)d_in[9];
  float* out = (float*)d_out;
  char* w = (char*)d_ws;

  constexpr size_t MB = 1u << 20;
  // h planes (f16, [8192][1024], hi scaled x64, lo = resid x64)
  f16* haH = (f16*)(w + 0 * MB);
  f16* haL = (f16*)(w + 16 * MB);
  f16* hbH = (f16*)(w + 32 * MB);
  f16* hbL = (f16*)(w + 48 * MB);
  // weight planes ([n][k] layout)
  f16* B0tH = (f16*)(w + 64 * MB); f16* B0tL = (f16*)(w + 66 * MB);   // W0^T
  f16* B12tH= (f16*)(w + 68 * MB); f16* B12tL= (f16*)(w + 70 * MB);   // W12^T
  f16* BssH = (f16*)(w + 72 * MB); f16* BssL = (f16*)(w + 74 * MB);   // R+R^T
  f16* B12H = (f16*)(w + 76 * MB); f16* B12L = (f16*)(w + 78 * MB);   // W12
  f16* B0H  = (f16*)(w + 80 * MB); f16* B0L  = (f16*)(w + 82 * MB);   // W0
  f16* BFH  = (f16*)(w + 84 * MB); f16* BFL  = (f16*)(w + 85 * MB + 512 * 1024); // F^T x3
  f16* BGH  = (f16*)(w + 87 * MB); f16* BGL  = (f16*)(w + 88 * MB + 512 * 1024); // G^T x3
  // small planes / vectors
  f16* MoTH   = (f16*)(w + 90 * MB);
  f16* MoTL   = (f16*)(w + 90 * MB + 128 * 1024);
  float* cvec = (float*)(w + 90 * MB + 256 * 1024);
  f16* A2H    = (f16*)(w + 91 * MB);
  f16* A2L    = (f16*)(w + 91 * MB + 128 * 1024);
  f16* xsH    = (f16*)(w + 92 * MB);   // split x planes, natural [b][t][k]
  f16* xsL    = (f16*)(w + 93 * MB);
  // temp W1/W2 split planes alias hb region (dead until first GEMM writes hb)
  f16* W1sH = (f16*)(w + 32 * MB); f16* W1sL = (f16*)(w + 34 * MB);
  f16* W2tH = (f16*)(w + 36 * MB); f16* W2tL = (f16*)(w + 38 * MB);

  const float* W0 = rotW;
  const float* W1 = rotW + (1u << 20);
  const float* W2 = rotW + (2u << 20);

  const dim3 blk(256);
  const size_t FGQ = (size_t)512 * 512;

  // ---- precompute: weight splits ----
  k_split     <<<dim3(1024), blk, 0, stream>>>(W1, W1sH, W1sL);                 // W1 [m][k]
  k_splitT    <<<dim3(16, 16), blk, 0, stream>>>(W2, W2tH, W2tL, DD);           // W2^T [n][k]
  // W12 = W1 @ W2 in split-f16 (BM=64 -> 128 blocks for occupancy)
  k_gemm16<64, false, 0><<<dim3(8, 16), blk, 0, stream>>>(W1sH, W1sL, DD, W2tH, W2tL, DD, B12H, B12L, DD, DD);
  k_tr16      <<<dim3(16, 16), blk, 0, stream>>>(B12H, B12tH, DD);              // W12^T planes
  k_tr16      <<<dim3(16, 16), blk, 0, stream>>>(B12L, B12tL, DD);
  k_symm_split<<<dim3(16, 16), blk, 0, stream>>>(R, BssH, BssL);
  k_splitT    <<<dim3(16, 16), blk, 0, stream>>>(W0, B0tH, B0tL, DD);           // W0^T
  k_split     <<<dim3(1024), blk, 0, stream>>>(W0, B0H, B0L);                   // W0 as-is
  k_splitT    <<<dim3(8, 8, 3), blk, 0, stream>>>(F, BFH, BFL, 512);            // F_i^T
  k_splitT    <<<dim3(8, 8, 3), blk, 0, stream>>>(G, BGH, BGL, 512);            // G_i^T
  k_split     <<<dim3(512), blk, 0, stream>>>(x, xsH, xsL);                     // x planes
  k_pwi       <<<dim3(256), blk, 0, stream>>>(P, Wi, A2H, A2L);
  k_pwo       <<<dim3(256), blk, 0, stream>>>(P, Wo, MoTH, MoTL);
  k_matvec    <<<dim3(256), blk, 0, stream>>>(P, bi, cvec);

  // ---- main pipeline ----
  // input projection (MFMA, pre-rolled -t via B-row staging)
  k_in_mfma<<<dim3(8, 128), blk, 0, stream>>>(xsH, xsL, A2H, A2L, cvec, haH, haL);

  // rotor 0 fwd (A pre-rolled, store +t)
  k_gemm16<128, false, +1><<<dim3(8, 64), blk, 0, stream>>>(haH, haL, DD, B0tH, B0tL, DD, hbH, hbL, DD, DD);
  // rotors 1,2 precomposed
  k_gemm16<128, false, 0><<<dim3(8, 64), blk, 0, stream>>>(hbH, hbL, DD, B12tH, B12tL, DD, haH, haL, DD, DD);
  // reversible blocks fwd (in place on ha; h2 = cols 512.., y1 = cols 0..)
  for (int i = 0; i < 3; ++i) {
    k_gemm16<64, true, 0><<<dim3(4, 128), blk, 0, stream>>>(haH + 512, haL + 512, DD, BFH + i * FGQ, BFL + i * FGQ, 512, haH, haL, DD, 512);
    k_gemm16<64, true, 0><<<dim3(4, 128), blk, 0, stream>>>(haH, haL, DD, BGH + i * FGQ, BGL + i * FGQ, 512, haH + 512, haL + 512, DD, 512);
  }
  // reflector
  k_gemm16<128, false, 0><<<dim3(8, 64), blk, 0, stream>>>(haH, haL, DD, BssH, BssL, DD, hbH, hbL, DD, DD);
  // reversible blocks reversed (in place on hb)
  for (int i = 2; i >= 0; --i) {
    k_gemm16<64, true, 0><<<dim3(4, 128), blk, 0, stream>>>(hbH + 512, hbL + 512, DD, BFH + i * FGQ, BFL + i * FGQ, 512, hbH, hbL, DD, 512);
    k_gemm16<64, true, 0><<<dim3(4, 128), blk, 0, stream>>>(hbH, hbL, DD, BGH + i * FGQ, BGL + i * FGQ, 512, hbH + 512, hbL + 512, DD, 512);
  }
  // rotors inverse: W12^T-mult (B = W12 as-is), store pre-rolled (-t)
  k_gemm16<128, false, -1><<<dim3(8, 64), blk, 0, stream>>>(hbH, hbL, DD, B12H, B12L, DD, haH, haL, DD, DD);
  // rotor 0 inverse: W0^T-mult (B = W0 as-is), store +t -> linear
  k_gemm16<128, false, +1><<<dim3(8, 64), blk, 0, stream>>>(haH, haL, DD, B0H, B0L, DD, hbH, hbL, DD, DD);

  // output projection (MFMA on already-split h planes)
  k_out_mfma<<<dim3(128), blk, 0, stream>>>(hbH, hbL, MoTH, MoTL, bo, out);
}